// Round 10
// baseline (308.963 us; speedup 1.0000x reference)
//
#include <hip/hip_runtime.h>

// z_e: [B=64, D=64, H=64, W=64] fp32 ; embeddings: [K=512, D=64] fp32
// out: z_q_st [64,64,64,64] fp32 ++ loss (1 fp32)
constexpr int Dc  = 64;
constexpr int Kc  = 512;
constexpr int HWc = 4096;
constexpr int Nc  = 64 * HWc;                    // 262144 points
constexpr float INV_ELEMS = 1.0f / 16777216.0f;
// 1-term metric: s = eh.zh - ||e||^2/2. s-error = |el.zh + eh.zl| ~ N(0,0.009).
// Window 0.10 ~ 11 sigma: points with (a1-a2) <= 0.10 get exact fp32 rescan.
constexpr float FLAG_HALF = 0.10f;

constexpr int LDS_EPOS = 65536;                  // after 64KB Eh fragments
constexpr int LDS_RED  = LDS_EPOS + 2048;
constexpr int LDS_TOT  = LDS_RED + 64;           // 67648 B -> 2 blocks/CU

typedef __attribute__((ext_vector_type(8))) short bf16x8;
typedef __attribute__((ext_vector_type(4))) float f32x4;

static __device__ __forceinline__ short f2bf(float x) {   // RNE fp32->bf16
    unsigned u = __builtin_bit_cast(unsigned, x);
    unsigned r = (u + 0x7FFFu + ((u >> 16) & 1u)) >> 16;
    return (short)r;
}
static __device__ __forceinline__ float bf2f(short h) {
    unsigned u = ((unsigned)(unsigned short)h) << 16;
    return __builtin_bit_cast(float, u);
}

// ---- K1: prep — pack Eh fragment stream (64KB) + eposneg -------------------
// q<4096: 16B chunk q: kt=q>>7, c=(q>>6)&1, lane=q&63;
// content = hi-bf16 of emb[kt*16+(lane&15)][c*32+(lane>>4)*8 .. +8).
// q in [4096,4608): eposneg[k] = -0.5*||e_k||^2, k = q-4096.
__global__ __launch_bounds__(256) void vq_prep(const float* __restrict__ emb,
                                               short* __restrict__ EF,
                                               float* __restrict__ eposneg) {
    int q = blockIdx.x * 256 + threadIdx.x;
    if (q < 4096) {
        int kt = q >> 7, c = (q >> 6) & 1, lane = q & 63;
        int code = kt * 16 + (lane & 15);
        int d0   = c * 32 + (lane >> 4) * 8;
        const float* e = emb + (size_t)code * Dc + d0;
        bf16x8 v;
#pragma unroll
        for (int j = 0; j < 8; ++j) v[j] = f2bf(e[j]);
        *reinterpret_cast<bf16x8*>(EF + (size_t)q * 8) = v;
    } else if (q < 4096 + Kc) {
        int k = q - 4096;
        const float* e = emb + (size_t)k * Dc;
        float s0 = 0.f, s1 = 0.f, s2 = 0.f, s3 = 0.f;
#pragma unroll
        for (int d = 0; d < 16; ++d) {
            float v0 = e[d], v1 = e[16 + d], v2 = e[32 + d], v3 = e[48 + d];
            s0 = fmaf(v0, v0, s0); s1 = fmaf(v1, v1, s1);
            s2 = fmaf(v2, v2, s2); s3 = fmaf(v3, v3, s3);
        }
        eposneg[k] = -0.5f * ((s0 + s1) + (s2 + s3));
    }
}

// ---- K2: main --------------------------------------------------------------
// 512 blocks x 1024 thr; 66KB LDS -> 2 blocks/CU -> 8 waves/SIMD (TLP hides
// all chain latency). Wave owns 32 points (2 MFMA tiles). Per kt: 2 ds_read +
// 4 MFMA (depth-2 chains) + inline argmax. Live regs ~50 < 64: NO spills.
__global__ __launch_bounds__(1024)
void vq_main(const float* __restrict__ z_e, const float* __restrict__ emb,
             const short* __restrict__ EF, const float* __restrict__ eposneg,
             float* __restrict__ out, float* __restrict__ acc,
             unsigned int* __restrict__ flags) {
    extern __shared__ __align__(16) char smem[];
    const int tid = threadIdx.x;

    // stage 64 KB Eh fragments + 2 KB eposneg
    {
        const bf16x8* src = reinterpret_cast<const bf16x8*>(EF);
        bf16x8*       dst = reinterpret_cast<bf16x8*>(smem);
#pragma unroll
        for (int i = 0; i < 4; ++i) dst[tid + i * 1024] = src[tid + i * 1024];
        if (tid < Kc) ((float*)(smem + LDS_EPOS))[tid] = eposneg[tid];
    }
    __syncthreads();
    const float* eposL = (const float*)(smem + LDS_EPOS);

    const int wave = tid >> 6, lane = tid & 63;
    const int p16 = lane & 15, g = lane >> 4;
    const int g4 = g * 4, lane16 = lane * 16;
    const int pbase = blockIdx.x * 512 + wave * 32;      // 32 points per wave
    const int b = pbase >> 12, hw0 = pbase & 4095;
    const float* zbase = z_e + (size_t)b * (Dc * HWc) + hw0;

    // Z hi fragments only: element j -> Z[d = c*32+g*8+j][point = t*16+p16]
    bf16x8 zh[2][2];
#pragma unroll
    for (int t = 0; t < 2; ++t)
#pragma unroll
        for (int c = 0; c < 2; ++c)
#pragma unroll
            for (int j = 0; j < 8; ++j)
                zh[t][c][j] = f2bf(zbase[(size_t)(c * 32 + g * 8 + j) * HWc + t * 16 + p16]);

    float a1[2] = {-3.4e38f, -3.4e38f}, a2[2] = {-3.4e38f, -3.4e38f};
    int   i1[2] = {0, 0};

#pragma unroll 1
    for (int kt = 0; kt < Kc / 16; ++kt) {
        const char* eb = smem + kt * 2048 + lane16;
        bf16x8 eh0 = *reinterpret_cast<const bf16x8*>(eb);
        bf16x8 eh1 = *reinterpret_cast<const bf16x8*>(eb + 1024);
        f32x4 en = *reinterpret_cast<const f32x4*>(eposL + kt * 16 + g4);
        f32x4 c0, c1;
        c0 = __builtin_amdgcn_mfma_f32_16x16x32_bf16(eh0, zh[0][0], en, 0, 0, 0);
        c1 = __builtin_amdgcn_mfma_f32_16x16x32_bf16(eh0, zh[1][0], en, 0, 0, 0);
        c0 = __builtin_amdgcn_mfma_f32_16x16x32_bf16(eh1, zh[0][1], c0, 0, 0, 0);
        c1 = __builtin_amdgcn_mfma_f32_16x16x32_bf16(eh1, zh[1][1], c1, 0, 0, 0);
#pragma unroll
        for (int r = 0; r < 4; ++r) {                    // code ascending in r
            float s0 = c0[r], s1 = c1[r];
            int code = kt * 16 + g4 + r;
            bool gt0 = s0 > a1[0];                       // strict: first-occurrence
            a2[0] = fmaxf(gt0 ? a1[0] : s0, a2[0]);
            i1[0] = gt0 ? code : i1[0];
            a1[0] = gt0 ? s0 : a1[0];
            bool gt1 = s1 > a1[1];
            a2[1] = fmaxf(gt1 ? a1[1] : s1, a2[1]);
            i1[1] = gt1 ? code : i1[1];
            a1[1] = gt1 ? s1 : a1[1];
        }
    }

    // merge (a1,i1,a2) across the 4 lane-groups (code subsets), per point
#pragma unroll
    for (int off = 16; off <= 32; off <<= 1)
#pragma unroll
        for (int t = 0; t < 2; ++t) {
            float oa1 = __shfl_xor(a1[t], off, 64);
            float oa2 = __shfl_xor(a2[t], off, 64);
            int   oi1 = __shfl_xor(i1[t], off, 64);
            float lo  = fminf(a1[t], oa1);
            a2[t] = fmaxf(fmaxf(a2[t], oa2), lo);
            bool take = (oa1 > a1[t]) || (oa1 == a1[t] && oi1 < i1[t]);
            a1[t] = take ? oa1 : a1[t];
            i1[t] = take ? oi1 : i1[t];
        }

    // flags: one 32-bit word per 32 points (this wave's exact span)
    unsigned m[2];
#pragma unroll
    for (int t = 0; t < 2; ++t) {
        bool flg = (a1[t] - a2[t]) <= FLAG_HALF;         // near-tie in approx metric
        m[t] = (unsigned)(__ballot(g == 0 && flg) & 0xFFFFull);
    }
    if (lane == 0) flags[pbase / 32] = m[0] | (m[1] << 16);

    // epilogue: gather exact fp32 code rows, write z_q, loss from zh
    // (zh-only z in loss: bias ~ E[zl^2] ~ 6e-7, negligible vs 8.75e-2)
    float lsum = 0.f;
#pragma unroll
    for (int t = 0; t < 2; ++t) {
        const float* er = emb + (size_t)i1[t] * Dc;
        float* op = out + (size_t)b * (Dc * HWc) + hw0 + t * 16 + p16;
#pragma unroll
        for (int c = 0; c < 2; ++c)
#pragma unroll
            for (int j = 0; j < 8; ++j) {
                int d = c * 32 + g * 8 + j;              // lane's own d-slots
                float e = er[d];
                op[(size_t)d * HWc] = e;
                float f = e - bf2f(zh[t][c][j]);
                lsum = fmaf(f, f, lsum);
            }
    }

    // block-level loss reduction -> one atomic per block
    float v = lsum;
#pragma unroll
    for (int off = 32; off > 0; off >>= 1) v += __shfl_down(v, off);
    float* red = (float*)(smem + LDS_RED);
    if (lane == 0) red[wave] = v;
    __syncthreads();
    if (tid == 0) {
        float bs = 0.f;
#pragma unroll
        for (int w = 0; w < 16; ++w) bs += red[w];
        atomicAdd(acc, bs);
    }
}

// ---- K3: exact fp32 fixup for flagged points -------------------------------
__global__ __launch_bounds__(256) void vq_fixup(const float* __restrict__ z_e,
                                                const float* __restrict__ emb,
                                                const float* __restrict__ eposneg,
                                                const unsigned int* __restrict__ flags,
                                                float* __restrict__ out,
                                                float* __restrict__ acc) {
    const int lane = threadIdx.x & 63;
    const int wid  = (blockIdx.x * 256 + threadIdx.x) >> 6;
    const int nw   = (gridDim.x * 256) >> 6;
    for (int w = wid; w < Nc / 32; w += nw) {
        unsigned f = flags[w];
        while (f) {
            int bit = __ffs(f) - 1; f &= f - 1;
            int p = w * 32 + bit;
            int b = p >> 12, hw = p & 4095;
            const float* zp = z_e + (size_t)b * (Dc * HWc) + hw;
            float z[Dc];
#pragma unroll
            for (int d = 0; d < Dc; ++d) z[d] = zp[(size_t)d * HWc];  // broadcast
            float bd = 3.4e38f; int bi = 0;
#pragma unroll 1
            for (int r = 0; r < 8; ++r) {                // codes r*64 + lane
                int code = r * 64 + lane;
                const float* er = emb + (size_t)code * Dc;
                float s0 = 0.f, s1 = 0.f, s2 = 0.f, s3 = 0.f;
#pragma unroll
                for (int d = 0; d < 16; ++d) {           // R1-proven numerics
                    s0 = fmaf(er[d],      z[d],      s0);
                    s1 = fmaf(er[16 + d], z[16 + d], s1);
                    s2 = fmaf(er[32 + d], z[32 + d], s2);
                    s3 = fmaf(er[48 + d], z[48 + d], s3);
                }
                float dot  = (s0 + s1) + (s2 + s3);
                float dist = fmaf(-2.0f, dot, -2.0f * eposneg[code]); // +||e||^2
                if (dist < bd) { bd = dist; bi = code; } // within-lane ascending
            }
#pragma unroll
            for (int off = 32; off > 0; off >>= 1) {     // cross-lane argmin
                float od = __shfl_xor(bd, off, 64);
                int   oi = __shfl_xor(bi, off, 64);
                bool take = (od < bd) || (od == bd && oi < bi);
                bd = take ? od : bd;
                bi = take ? oi : bi;
            }
            // patch z_q column + loss delta (lane = d)
            float* op = out + (size_t)b * (Dc * HWc) + (size_t)lane * HWc + hw;
            float eo = *op;
            float en = emb[(size_t)bi * Dc + lane];
            float zf = zp[(size_t)lane * HWc];
            float dn = en - zf, dold = eo - zf;
            float delta = fmaf(dn, dn, -dold * dold);
            *op = en;
#pragma unroll
            for (int off = 32; off > 0; off >>= 1) delta += __shfl_down(delta, off);
            if (lane == 0) atomicAdd(acc, delta);
        }
    }
}

// ---- K4: finalize loss -----------------------------------------------------
__global__ void vq_finalize(const float* __restrict__ acc, float* __restrict__ out_loss) {
    out_loss[0] = 1.25f * (acc[0] * INV_ELEMS);
}

extern "C" void kernel_launch(void* const* d_in, const int* in_sizes, int n_in,
                              void* d_out, int out_size, void* d_ws, size_t ws_size,
                              hipStream_t stream) {
    const float* z_e = (const float*)d_in[0];
    const float* emb = (const float*)d_in[1];
    float* out = (float*)d_out;

    char* ws = (char*)d_ws;
    float*    acc     = (float*)(ws);                 // 4 B
    float*    eposneg = (float*)(ws + 256);           // 512 f32 = 2 KB
    unsigned* flags   = (unsigned*)(ws + 4096);       // N/32 u32 = 32 KB
    short*    EF      = (short*)(ws + 65536);         // 64 KB Eh fragment stream

    hipFuncSetAttribute(reinterpret_cast<const void*>(vq_main),
                        hipFuncAttributeMaxDynamicSharedMemorySize, LDS_TOT);

    hipMemsetAsync(acc, 0, sizeof(float), stream);
    vq_prep<<<18, 256, 0, stream>>>(emb, EF, eposneg);
    vq_main<<<Nc / 512, 1024, LDS_TOT, stream>>>(z_e, emb, EF, eposneg, out, acc, flags);
    vq_fixup<<<256, 256, 0, stream>>>(z_e, emb, eposneg, flags, out, acc);
    vq_finalize<<<1, 1, 0, stream>>>(acc, out + (size_t)Nc * Dc);
}

// Round 11
// 136.429 us; speedup vs baseline: 2.2646x; 2.2646x over previous
//
#include <hip/hip_runtime.h>

// z_e: [B=64, D=64, H=64, W=64] fp32 ; embeddings: [K=512, D=64] fp32
// out: z_q_st [64,64,64,64] fp32 ++ loss (1 fp32)
constexpr int Dc  = 64;
constexpr int Kc  = 512;
constexpr int HWc = 4096;
constexpr int Nc  = 64 * HWc;                    // 262144 points
constexpr float INV_ELEMS = 1.0f / 16777216.0f;
// fp16 1-term metric: s = eh.zh - ||e||^2/2. s-error = eh.zl + el.zh + el.zl,
// sigma_s ~ 1.8e-3 (fp16 rms conv err 1.6e-4, 64-dim CLT). FLAG_HALF = 0.02
// = 7.8 sigma of the PAIRWISE error: points with (a1-a2) <= 0.02 get exact
// fp32 rescan; unflagged points are argmin-correct w.p. 1-1e-9.
constexpr float FLAG_HALF = 0.02f;

constexpr int LDS_EPOS = 65536;                  // after 64KB Eh fragments
constexpr int LDS_RED  = LDS_EPOS + 2048;
constexpr int LDS_TOT  = LDS_RED + 64;           // 67648 B -> 2 blocks/CU

typedef __attribute__((ext_vector_type(8))) _Float16 half8;
typedef __attribute__((ext_vector_type(4))) float    f32x4;

static __device__ __forceinline__ short f2h(float x) {   // RNE fp32->fp16
    _Float16 h = (_Float16)x;
    return __builtin_bit_cast(short, h);
}

// ---- K1: prep — pack E-fp16 fragment stream (64KB) + eposneg ---------------
// q<4096: 16B chunk q: kt=q>>7, c=(q>>6)&1, lane=q&63;
// content = fp16 of emb[kt*16+(lane&15)][c*32+(lane>>4)*8 .. +8).
// q in [4096,4608): eposneg[k] = -0.5*||e_k||^2, k = q-4096.
__global__ __launch_bounds__(256) void vq_prep(const float* __restrict__ emb,
                                               short* __restrict__ EF,
                                               float* __restrict__ eposneg) {
    int q = blockIdx.x * 256 + threadIdx.x;
    if (q < 4096) {
        int kt = q >> 7, c = (q >> 6) & 1, lane = q & 63;
        int code = kt * 16 + (lane & 15);
        int d0   = c * 32 + (lane >> 4) * 8;
        const float* e = emb + (size_t)code * Dc + d0;
        short v[8];
#pragma unroll
        for (int j = 0; j < 8; ++j) v[j] = f2h(e[j]);
        *reinterpret_cast<int4*>(EF + (size_t)q * 8) = *reinterpret_cast<int4*>(v);
    } else if (q < 4096 + Kc) {
        int k = q - 4096;
        const float* e = emb + (size_t)k * Dc;
        float s0 = 0.f, s1 = 0.f, s2 = 0.f, s3 = 0.f;
#pragma unroll
        for (int d = 0; d < 16; ++d) {
            float v0 = e[d], v1 = e[16 + d], v2 = e[32 + d], v3 = e[48 + d];
            s0 = fmaf(v0, v0, s0); s1 = fmaf(v1, v1, s1);
            s2 = fmaf(v2, v2, s2); s3 = fmaf(v3, v3, s3);
        }
        eposneg[k] = -0.5f * ((s0 + s1) + (s2 + s3));
    }
}

// ---- K2: main (R10 structure, fp16 operands) -------------------------------
// 512 blocks x 1024 thr; 66KB LDS -> 2 blocks/CU -> 8 waves/SIMD. Wave owns
// 32 points (2 MFMA tiles). Per kt: 2 ds_read + 4 MFMA (depth-2) + argmax.
__global__ __launch_bounds__(1024)
void vq_main(const float* __restrict__ z_e, const float* __restrict__ emb,
             const short* __restrict__ EF, const float* __restrict__ eposneg,
             float* __restrict__ out, float* __restrict__ acc,
             unsigned int* __restrict__ flags) {
    extern __shared__ __align__(16) char smem[];
    const int tid = threadIdx.x;

    // stage 64 KB E-fp16 fragments + 2 KB eposneg
    {
        const int4* src = reinterpret_cast<const int4*>(EF);
        int4*       dst = reinterpret_cast<int4*>(smem);
#pragma unroll
        for (int i = 0; i < 4; ++i) dst[tid + i * 1024] = src[tid + i * 1024];
        if (tid < Kc) ((float*)(smem + LDS_EPOS))[tid] = eposneg[tid];
    }
    __syncthreads();
    const float* eposL = (const float*)(smem + LDS_EPOS);

    const int wave = tid >> 6, lane = tid & 63;
    const int p16 = lane & 15, g = lane >> 4;
    const int g4 = g * 4, lane16 = lane * 16;
    const int pbase = blockIdx.x * 512 + wave * 32;      // 32 points per wave
    const int b = pbase >> 12, hw0 = pbase & 4095;
    const float* zbase = z_e + (size_t)b * (Dc * HWc) + hw0;

    // Z fp16 fragments: element j -> Z[d = c*32+g*8+j][point = t*16+p16]
    half8 zh[2][2];
#pragma unroll
    for (int t = 0; t < 2; ++t)
#pragma unroll
        for (int c = 0; c < 2; ++c)
#pragma unroll
            for (int j = 0; j < 8; ++j)
                zh[t][c][j] = (_Float16)zbase[(size_t)(c * 32 + g * 8 + j) * HWc + t * 16 + p16];

    float a1[2] = {-3.4e38f, -3.4e38f}, a2[2] = {-3.4e38f, -3.4e38f};
    int   i1[2] = {0, 0};

#pragma unroll 1
    for (int kt = 0; kt < Kc / 16; ++kt) {
        const char* eb = smem + kt * 2048 + lane16;
        half8 eh0 = *reinterpret_cast<const half8*>(eb);
        half8 eh1 = *reinterpret_cast<const half8*>(eb + 1024);
        f32x4 en = *reinterpret_cast<const f32x4*>(eposL + kt * 16 + g4);
        f32x4 c0, c1;
        c0 = __builtin_amdgcn_mfma_f32_16x16x32_f16(eh0, zh[0][0], en, 0, 0, 0);
        c1 = __builtin_amdgcn_mfma_f32_16x16x32_f16(eh0, zh[1][0], en, 0, 0, 0);
        c0 = __builtin_amdgcn_mfma_f32_16x16x32_f16(eh1, zh[0][1], c0, 0, 0, 0);
        c1 = __builtin_amdgcn_mfma_f32_16x16x32_f16(eh1, zh[1][1], c1, 0, 0, 0);
#pragma unroll
        for (int r = 0; r < 4; ++r) {                    // code ascending in r
            float s0 = c0[r], s1 = c1[r];
            int code = kt * 16 + g4 + r;
            bool gt0 = s0 > a1[0];                       // strict: first-occurrence
            a2[0] = fmaxf(gt0 ? a1[0] : s0, a2[0]);
            i1[0] = gt0 ? code : i1[0];
            a1[0] = gt0 ? s0 : a1[0];
            bool gt1 = s1 > a1[1];
            a2[1] = fmaxf(gt1 ? a1[1] : s1, a2[1]);
            i1[1] = gt1 ? code : i1[1];
            a1[1] = gt1 ? s1 : a1[1];
        }
    }

    // merge (a1,i1,a2) across the 4 lane-groups (code subsets), per point
#pragma unroll
    for (int off = 16; off <= 32; off <<= 1)
#pragma unroll
        for (int t = 0; t < 2; ++t) {
            float oa1 = __shfl_xor(a1[t], off, 64);
            float oa2 = __shfl_xor(a2[t], off, 64);
            int   oi1 = __shfl_xor(i1[t], off, 64);
            float lo  = fminf(a1[t], oa1);
            a2[t] = fmaxf(fmaxf(a2[t], oa2), lo);
            bool take = (oa1 > a1[t]) || (oa1 == a1[t] && oi1 < i1[t]);
            a1[t] = take ? oa1 : a1[t];
            i1[t] = take ? oi1 : i1[t];
        }

    // flags: one 32-bit word per 32 points (this wave's exact span)
    unsigned m[2];
#pragma unroll
    for (int t = 0; t < 2; ++t) {
        bool flg = (a1[t] - a2[t]) <= FLAG_HALF;         // near-tie in approx metric
        m[t] = (unsigned)(__ballot(g == 0 && flg) & 0xFFFFull);
    }
    if (lane == 0) flags[pbase / 32] = m[0] | (m[1] << 16);

    // epilogue: gather exact fp32 code rows, write z_q, loss from zh
    // (fp16 zh in loss: bias ~ E[zl^2] ~ 3e-8, negligible vs 8.75e-2)
    float lsum = 0.f;
#pragma unroll
    for (int t = 0; t < 2; ++t) {
        const float* er = emb + (size_t)i1[t] * Dc;
        float* op = out + (size_t)b * (Dc * HWc) + hw0 + t * 16 + p16;
#pragma unroll
        for (int c = 0; c < 2; ++c)
#pragma unroll
            for (int j = 0; j < 8; ++j) {
                int d = c * 32 + g * 8 + j;              // lane's own d-slots
                float e = er[d];
                op[(size_t)d * HWc] = e;
                float f = e - (float)zh[t][c][j];
                lsum = fmaf(f, f, lsum);
            }
    }

    // block-level loss reduction -> one atomic per block
    float v = lsum;
#pragma unroll
    for (int off = 32; off > 0; off >>= 1) v += __shfl_down(v, off);
    float* red = (float*)(smem + LDS_RED);
    if (lane == 0) red[wave] = v;
    __syncthreads();
    if (tid == 0) {
        float bs = 0.f;
#pragma unroll
        for (int w = 0; w < 16; ++w) bs += red[w];
        atomicAdd(acc, bs);
    }
}

// ---- K3: exact fp32 fixup for flagged points (rewritten memory path) -------
// z staged once per point: ONE lane-parallel global load -> LDS, then read
// back as broadcast ds_read_b128. e rows as float4. Accumulation order is
// EXACTLY R1's proven s0..s3 d-sequential order (same bits, same decisions).
__global__ __launch_bounds__(256) void vq_fixup(const float* __restrict__ z_e,
                                                const float* __restrict__ emb,
                                                const float* __restrict__ eposneg,
                                                const unsigned int* __restrict__ flags,
                                                float* __restrict__ out,
                                                float* __restrict__ acc) {
    __shared__ __align__(16) float zsh[4][64];
    const int lane = threadIdx.x & 63;
    const int wv   = threadIdx.x >> 6;
    const int wid  = (blockIdx.x * 256 + threadIdx.x) >> 6;
    const int nw   = (gridDim.x * 256) >> 6;
    for (int w = wid; w < Nc / 32; w += nw) {
        unsigned f = flags[w];
        while (f) {
            int bit = __ffs(f) - 1; f &= f - 1;
            int p = w * 32 + bit;
            int b = p >> 12, hw = p & 4095;
            const float* zp = z_e + (size_t)b * (Dc * HWc) + hw;
            zsh[wv][lane] = zp[(size_t)lane * HWc];      // one scattered load
            asm volatile("s_waitcnt lgkmcnt(0)" ::: "memory");  // intra-wave order
            const float4* z4 = reinterpret_cast<const float4*>(zsh[wv]);
            float bd = 3.4e38f; int bi = 0;
#pragma unroll 1
            for (int r = 0; r < 8; ++r) {                // codes r*64 + lane
                int code = r * 64 + lane;
                const float4* er4 = reinterpret_cast<const float4*>(emb + (size_t)code * Dc);
                float s0 = 0.f, s1 = 0.f, s2 = 0.f, s3 = 0.f;
#pragma unroll
                for (int q = 0; q < 4; ++q) {            // d order 0..15 per chain
                    float4 e0 = er4[q],      zz0 = z4[q];
                    float4 e1 = er4[4 + q],  zz1 = z4[4 + q];
                    float4 e2 = er4[8 + q],  zz2 = z4[8 + q];
                    float4 e3 = er4[12 + q], zz3 = z4[12 + q];
                    s0 = fmaf(e0.x, zz0.x, s0); s0 = fmaf(e0.y, zz0.y, s0);
                    s0 = fmaf(e0.z, zz0.z, s0); s0 = fmaf(e0.w, zz0.w, s0);
                    s1 = fmaf(e1.x, zz1.x, s1); s1 = fmaf(e1.y, zz1.y, s1);
                    s1 = fmaf(e1.z, zz1.z, s1); s1 = fmaf(e1.w, zz1.w, s1);
                    s2 = fmaf(e2.x, zz2.x, s2); s2 = fmaf(e2.y, zz2.y, s2);
                    s2 = fmaf(e2.z, zz2.z, s2); s2 = fmaf(e2.w, zz2.w, s2);
                    s3 = fmaf(e3.x, zz3.x, s3); s3 = fmaf(e3.y, zz3.y, s3);
                    s3 = fmaf(e3.z, zz3.z, s3); s3 = fmaf(e3.w, zz3.w, s3);
                }
                float dot  = (s0 + s1) + (s2 + s3);
                float dist = fmaf(-2.0f, dot, -2.0f * eposneg[code]); // +||e||^2
                if (dist < bd) { bd = dist; bi = code; } // within-lane ascending
            }
#pragma unroll
            for (int off = 32; off > 0; off >>= 1) {     // cross-lane argmin
                float od = __shfl_xor(bd, off, 64);
                int   oi = __shfl_xor(bi, off, 64);
                bool take = (od < bd) || (od == bd && oi < bi);
                bd = take ? od : bd;
                bi = take ? oi : bi;
            }
            // patch z_q column + loss delta (lane = d)
            float* op = out + (size_t)b * (Dc * HWc) + (size_t)lane * HWc + hw;
            float eo = *op;
            float en = emb[(size_t)bi * Dc + lane];
            float zf = zsh[wv][lane];
            float dn = en - zf, dold = eo - zf;
            float delta = fmaf(dn, dn, -dold * dold);
            *op = en;
#pragma unroll
            for (int off = 32; off > 0; off >>= 1) delta += __shfl_down(delta, off);
            if (lane == 0) atomicAdd(acc, delta);
        }
    }
}

// ---- K4: finalize loss -----------------------------------------------------
__global__ void vq_finalize(const float* __restrict__ acc, float* __restrict__ out_loss) {
    out_loss[0] = 1.25f * (acc[0] * INV_ELEMS);
}

extern "C" void kernel_launch(void* const* d_in, const int* in_sizes, int n_in,
                              void* d_out, int out_size, void* d_ws, size_t ws_size,
                              hipStream_t stream) {
    const float* z_e = (const float*)d_in[0];
    const float* emb = (const float*)d_in[1];
    float* out = (float*)d_out;

    char* ws = (char*)d_ws;
    float*    acc     = (float*)(ws);                 // 4 B
    float*    eposneg = (float*)(ws + 256);           // 512 f32 = 2 KB
    unsigned* flags   = (unsigned*)(ws + 4096);       // N/32 u32 = 32 KB
    short*    EF      = (short*)(ws + 65536);         // 64 KB fp16 fragment stream

    hipFuncSetAttribute(reinterpret_cast<const void*>(vq_main),
                        hipFuncAttributeMaxDynamicSharedMemorySize, LDS_TOT);

    hipMemsetAsync(acc, 0, sizeof(float), stream);
    vq_prep<<<18, 256, 0, stream>>>(emb, EF, eposneg);
    vq_main<<<Nc / 512, 1024, LDS_TOT, stream>>>(z_e, emb, EF, eposneg, out, acc, flags);
    vq_fixup<<<512, 256, 0, stream>>>(z_e, emb, eposneg, flags, out, acc);
    vq_finalize<<<1, 1, 0, stream>>>(acc, out + (size_t)Nc * Dc);
}

// Round 12
// 125.840 us; speedup vs baseline: 2.4552x; 1.0842x over previous
//
#include <hip/hip_runtime.h>

// z_e: [B=64, D=64, H=64, W=64] fp32 ; embeddings: [K=512, D=64] fp32
// out: z_q_st [64,64,64,64] fp32 ++ loss (1 fp32)
constexpr int Dc  = 64;
constexpr int Kc  = 512;
constexpr int HWc = 4096;
constexpr int Nc  = 64 * HWc;                    // 262144 points
constexpr float INV_ELEMS = 1.0f / 16777216.0f;
// fp16 1-term metric: s = eh.zh - ||e||^2/2. sigma_s ~ 1.8e-3 (fp16 conv err,
// 64-dim CLT). FLAG_HALF = 0.02 ~ 7.8 sigma of the pairwise error: points with
// (a1-a2) <= 0.02 get exact fp32 rescan; others argmin-correct w.p. ~1-1e-9.
constexpr float FLAG_HALF = 0.02f;

constexpr int LDS_EPOS = 65536;                  // after 64KB E-fp16 fragments
constexpr int LDS_RED  = LDS_EPOS + 2048;
constexpr int LDS_TOT  = LDS_RED + 64;           // 67648 B -> 2 blocks/CU

constexpr int WL_OFF = 69632;                    // worklist byte offset in ws

typedef __attribute__((ext_vector_type(8))) _Float16 half8;
typedef __attribute__((ext_vector_type(4))) float    f32x4;

static __device__ __forceinline__ short f2h(float x) {   // RNE fp32->fp16
    _Float16 h = (_Float16)x;
    return __builtin_bit_cast(short, h);
}

// ---- K1: prep — pack E-fp16 fragment stream (64KB) + eposneg ---------------
__global__ __launch_bounds__(256) void vq_prep(const float* __restrict__ emb,
                                               short* __restrict__ EF,
                                               float* __restrict__ eposneg) {
    int q = blockIdx.x * 256 + threadIdx.x;
    if (q < 4096) {
        int kt = q >> 7, c = (q >> 6) & 1, lane = q & 63;
        int code = kt * 16 + (lane & 15);
        int d0   = c * 32 + (lane >> 4) * 8;
        const float* e = emb + (size_t)code * Dc + d0;
        short v[8];
#pragma unroll
        for (int j = 0; j < 8; ++j) v[j] = f2h(e[j]);
        *reinterpret_cast<int4*>(EF + (size_t)q * 8) = *reinterpret_cast<int4*>(v);
    } else if (q < 4096 + Kc) {
        int k = q - 4096;
        const float* e = emb + (size_t)k * Dc;
        float s0 = 0.f, s1 = 0.f, s2 = 0.f, s3 = 0.f;
#pragma unroll
        for (int d = 0; d < 16; ++d) {
            float v0 = e[d], v1 = e[16 + d], v2 = e[32 + d], v3 = e[48 + d];
            s0 = fmaf(v0, v0, s0); s1 = fmaf(v1, v1, s1);
            s2 = fmaf(v2, v2, s2); s3 = fmaf(v3, v3, s3);
        }
        eposneg[k] = -0.5f * ((s0 + s1) + (s2 + s3));
    }
}

// ---- K2: main (R11 structure; flags -> compacted worklist) -----------------
// 512 blocks x 1024 thr; 66KB LDS -> 2 blocks/CU -> 8 waves/SIMD. Wave owns
// 32 points (2 MFMA tiles). Per kt: 2 ds_read + 4 MFMA (depth-2) + argmax.
__global__ __launch_bounds__(1024)
void vq_main(const float* __restrict__ z_e, const float* __restrict__ emb,
             const short* __restrict__ EF, const float* __restrict__ eposneg,
             float* __restrict__ out, float* __restrict__ acc,
             unsigned int* __restrict__ cnt, unsigned int* __restrict__ wl,
             unsigned int wcap) {
    extern __shared__ __align__(16) char smem[];
    const int tid = threadIdx.x;

    // stage 64 KB E-fp16 fragments + 2 KB eposneg
    {
        const int4* src = reinterpret_cast<const int4*>(EF);
        int4*       dst = reinterpret_cast<int4*>(smem);
#pragma unroll
        for (int i = 0; i < 4; ++i) dst[tid + i * 1024] = src[tid + i * 1024];
        if (tid < Kc) ((float*)(smem + LDS_EPOS))[tid] = eposneg[tid];
    }
    __syncthreads();
    const float* eposL = (const float*)(smem + LDS_EPOS);

    const int wave = tid >> 6, lane = tid & 63;
    const int p16 = lane & 15, g = lane >> 4;
    const int g4 = g * 4, lane16 = lane * 16;
    const int pbase = blockIdx.x * 512 + wave * 32;      // 32 points per wave
    const int b = pbase >> 12, hw0 = pbase & 4095;
    const float* zbase = z_e + (size_t)b * (Dc * HWc) + hw0;

    // Z fp16 fragments: element j -> Z[d = c*32+g*8+j][point = t*16+p16]
    half8 zh[2][2];
#pragma unroll
    for (int t = 0; t < 2; ++t)
#pragma unroll
        for (int c = 0; c < 2; ++c)
#pragma unroll
            for (int j = 0; j < 8; ++j)
                zh[t][c][j] = (_Float16)zbase[(size_t)(c * 32 + g * 8 + j) * HWc + t * 16 + p16];

    float a1[2] = {-3.4e38f, -3.4e38f}, a2[2] = {-3.4e38f, -3.4e38f};
    int   i1[2] = {0, 0};

#pragma unroll 1
    for (int kt = 0; kt < Kc / 16; ++kt) {
        const char* eb = smem + kt * 2048 + lane16;
        half8 eh0 = *reinterpret_cast<const half8*>(eb);
        half8 eh1 = *reinterpret_cast<const half8*>(eb + 1024);
        f32x4 en = *reinterpret_cast<const f32x4*>(eposL + kt * 16 + g4);
        f32x4 c0, c1;
        c0 = __builtin_amdgcn_mfma_f32_16x16x32_f16(eh0, zh[0][0], en, 0, 0, 0);
        c1 = __builtin_amdgcn_mfma_f32_16x16x32_f16(eh0, zh[1][0], en, 0, 0, 0);
        c0 = __builtin_amdgcn_mfma_f32_16x16x32_f16(eh1, zh[0][1], c0, 0, 0, 0);
        c1 = __builtin_amdgcn_mfma_f32_16x16x32_f16(eh1, zh[1][1], c1, 0, 0, 0);
#pragma unroll
        for (int r = 0; r < 4; ++r) {                    // code ascending in r
            float s0 = c0[r], s1 = c1[r];
            int code = kt * 16 + g4 + r;
            bool gt0 = s0 > a1[0];                       // strict: first-occurrence
            a2[0] = fmaxf(gt0 ? a1[0] : s0, a2[0]);
            i1[0] = gt0 ? code : i1[0];
            a1[0] = gt0 ? s0 : a1[0];
            bool gt1 = s1 > a1[1];
            a2[1] = fmaxf(gt1 ? a1[1] : s1, a2[1]);
            i1[1] = gt1 ? code : i1[1];
            a1[1] = gt1 ? s1 : a1[1];
        }
    }

    // merge (a1,i1,a2) across the 4 lane-groups (code subsets), per point
#pragma unroll
    for (int off = 16; off <= 32; off <<= 1)
#pragma unroll
        for (int t = 0; t < 2; ++t) {
            float oa1 = __shfl_xor(a1[t], off, 64);
            float oa2 = __shfl_xor(a2[t], off, 64);
            int   oi1 = __shfl_xor(i1[t], off, 64);
            float lo  = fminf(a1[t], oa1);
            a2[t] = fmaxf(fmaxf(a2[t], oa2), lo);
            bool take = (oa1 > a1[t]) || (oa1 == a1[t] && oi1 < i1[t]);
            a1[t] = take ? oa1 : a1[t];
            i1[t] = take ? oi1 : i1[t];
        }

    // worklist append (wave-aggregated): bit l of mask -> point pbase+l flagged
    unsigned m[2];
#pragma unroll
    for (int t = 0; t < 2; ++t) {
        bool flg = (a1[t] - a2[t]) <= FLAG_HALF;         // near-tie in approx metric
        m[t] = (unsigned)(__ballot(g == 0 && flg) & 0xFFFFull);
    }
    unsigned mask = m[0] | (m[1] << 16);
    int npts = __popc(mask);
    unsigned wbase = 0;
    if (lane == 0 && npts) wbase = atomicAdd(cnt, (unsigned)npts);
    wbase = __shfl(wbase, 0, 64);
    if (lane < 32 && ((mask >> lane) & 1u)) {
        unsigned pos = wbase + __popc(mask & ((1u << lane) - 1u));
        if (pos < wcap) wl[pos] = (unsigned)(pbase + lane);
    }

    // epilogue: gather exact fp32 code rows, write z_q, loss from zh
    // (fp16 zh in loss: bias ~ 3e-8, negligible vs 8.75e-2 threshold)
    float lsum = 0.f;
#pragma unroll
    for (int t = 0; t < 2; ++t) {
        const float* er = emb + (size_t)i1[t] * Dc;
        float* op = out + (size_t)b * (Dc * HWc) + hw0 + t * 16 + p16;
#pragma unroll
        for (int c = 0; c < 2; ++c)
#pragma unroll
            for (int j = 0; j < 8; ++j) {
                int d = c * 32 + g * 8 + j;              // lane's own d-slots
                float e = er[d];
                op[(size_t)d * HWc] = e;
                float f = e - (float)zh[t][c][j];
                lsum = fmaf(f, f, lsum);
            }
    }

    // block-level loss reduction -> one atomic per block
    float v = lsum;
#pragma unroll
    for (int off = 32; off > 0; off >>= 1) v += __shfl_down(v, off);
    float* red = (float*)(smem + LDS_RED);
    if (lane == 0) red[wave] = v;
    __syncthreads();
    if (tid == 0) {
        float bs = 0.f;
#pragma unroll
        for (int w = 0; w < 16; ++w) bs += red[w];
        atomicAdd(acc, bs);
    }
}

// ---- K3: exact fp32 fixup, grid-stride over compacted worklist -------------
// Per point: one lane-parallel z stage -> LDS broadcast; float4 e rows;
// accumulation order EXACTLY R1's proven order (same bits, same decisions).
__global__ __launch_bounds__(256) void vq_fixup(const float* __restrict__ z_e,
                                                const float* __restrict__ emb,
                                                const float* __restrict__ eposneg,
                                                const unsigned int* __restrict__ wl,
                                                const unsigned int* __restrict__ cnt,
                                                unsigned int wcap,
                                                float* __restrict__ out,
                                                float* __restrict__ acc) {
    __shared__ __align__(16) float zsh[4][64];
    const unsigned n = min(*cnt, wcap);
    const int lane = threadIdx.x & 63;
    const int wv   = threadIdx.x >> 6;
    const unsigned wid = (blockIdx.x * 256 + threadIdx.x) >> 6;
    const unsigned nw  = (gridDim.x * 256) >> 6;
    for (unsigned i = wid; i < n; i += nw) {
        int p = (int)wl[i];
        int b = p >> 12, hw = p & 4095;
        const float* zp = z_e + (size_t)b * (Dc * HWc) + hw;
        zsh[wv][lane] = zp[(size_t)lane * HWc];          // one scattered load
        asm volatile("s_waitcnt lgkmcnt(0)" ::: "memory");
        const float4* z4 = reinterpret_cast<const float4*>(zsh[wv]);
        float bd = 3.4e38f; int bi = 0;
#pragma unroll 2
        for (int r = 0; r < 8; ++r) {                    // codes r*64 + lane
            int code = r * 64 + lane;
            const float4* er4 = reinterpret_cast<const float4*>(emb + (size_t)code * Dc);
            float s0 = 0.f, s1 = 0.f, s2 = 0.f, s3 = 0.f;
#pragma unroll
            for (int q = 0; q < 4; ++q) {                // d order 0..15 per chain
                float4 e0 = er4[q],      zz0 = z4[q];
                float4 e1 = er4[4 + q],  zz1 = z4[4 + q];
                float4 e2 = er4[8 + q],  zz2 = z4[8 + q];
                float4 e3 = er4[12 + q], zz3 = z4[12 + q];
                s0 = fmaf(e0.x, zz0.x, s0); s0 = fmaf(e0.y, zz0.y, s0);
                s0 = fmaf(e0.z, zz0.z, s0); s0 = fmaf(e0.w, zz0.w, s0);
                s1 = fmaf(e1.x, zz1.x, s1); s1 = fmaf(e1.y, zz1.y, s1);
                s1 = fmaf(e1.z, zz1.z, s1); s1 = fmaf(e1.w, zz1.w, s1);
                s2 = fmaf(e2.x, zz2.x, s2); s2 = fmaf(e2.y, zz2.y, s2);
                s2 = fmaf(e2.z, zz2.z, s2); s2 = fmaf(e2.w, zz2.w, s2);
                s3 = fmaf(e3.x, zz3.x, s3); s3 = fmaf(e3.y, zz3.y, s3);
                s3 = fmaf(e3.z, zz3.z, s3); s3 = fmaf(e3.w, zz3.w, s3);
            }
            float dot  = (s0 + s1) + (s2 + s3);
            float dist = fmaf(-2.0f, dot, -2.0f * eposneg[code]);  // +||e||^2
            if (dist < bd) { bd = dist; bi = code; }     // within-lane ascending
        }
#pragma unroll
        for (int off = 32; off > 0; off >>= 1) {         // cross-lane argmin
            float od = __shfl_xor(bd, off, 64);
            int   oi = __shfl_xor(bi, off, 64);
            bool take = (od < bd) || (od == bd && oi < bi);
            bd = take ? od : bd;
            bi = take ? oi : bi;
        }
        // patch z_q column + loss delta (lane = d)
        float* op = out + (size_t)b * (Dc * HWc) + (size_t)lane * HWc + hw;
        float eo = *op;
        float en = emb[(size_t)bi * Dc + lane];
        float zf = zsh[wv][lane];
        float dn = en - zf, dold = eo - zf;
        float delta = fmaf(dn, dn, -dold * dold);
        *op = en;
#pragma unroll
        for (int off = 32; off > 0; off >>= 1) delta += __shfl_down(delta, off);
        if (lane == 0) atomicAdd(acc, delta);
    }
}

// ---- K4: finalize loss -----------------------------------------------------
__global__ void vq_finalize(const float* __restrict__ acc, float* __restrict__ out_loss) {
    out_loss[0] = 1.25f * (acc[0] * INV_ELEMS);
}

extern "C" void kernel_launch(void* const* d_in, const int* in_sizes, int n_in,
                              void* d_out, int out_size, void* d_ws, size_t ws_size,
                              hipStream_t stream) {
    const float* z_e = (const float*)d_in[0];
    const float* emb = (const float*)d_in[1];
    float* out = (float*)d_out;

    char* ws = (char*)d_ws;
    float*    acc     = (float*)(ws);                 // 4 B
    unsigned* cnt     = (unsigned*)(ws + 4);          // 4 B worklist counter
    float*    eposneg = (float*)(ws + 256);           // 512 f32 = 2 KB
    short*    EF      = (short*)(ws + 4096);          // 64 KB fp16 fragment stream
    unsigned* wl      = (unsigned*)(ws + WL_OFF);     // worklist (rest of ws)

    unsigned wcap = 0;
    if (ws_size > (size_t)WL_OFF + 4)
        wcap = (unsigned)min((size_t)Nc, (ws_size - WL_OFF) / 4);

    hipFuncSetAttribute(reinterpret_cast<const void*>(vq_main),
                        hipFuncAttributeMaxDynamicSharedMemorySize, LDS_TOT);

    hipMemsetAsync(ws, 0, 8, stream);                 // acc + cnt
    vq_prep<<<18, 256, 0, stream>>>(emb, EF, eposneg);
    vq_main<<<Nc / 512, 1024, LDS_TOT, stream>>>(z_e, emb, EF, eposneg, out, acc,
                                                 cnt, wl, wcap);
    vq_fixup<<<1024, 256, 0, stream>>>(z_e, emb, eposneg, wl, cnt, wcap, out, acc);
    vq_finalize<<<1, 1, 0, stream>>>(acc, out + (size_t)Nc * Dc);
}

// Round 13
// 115.309 us; speedup vs baseline: 2.6794x; 1.0913x over previous
//
#include <hip/hip_runtime.h>

// z_e: [B=64, D=64, H=64, W=64] fp32 ; embeddings: [K=512, D=64] fp32
// out: z_q_st [64,64,64,64] fp32 ++ loss (1 fp32)
constexpr int Dc  = 64;
constexpr int Kc  = 512;
constexpr int HWc = 4096;
constexpr int Nc  = 64 * HWc;                    // 262144 points
constexpr float INV_ELEMS = 1.0f / 16777216.0f;
// fp16 1-term metric: s = eh.zh - ||e||^2/2. sigma_s ~ 1.8e-3 (fp16 conv err,
// 64-dim CLT). FLAG_HALF = 0.02 ~ 7.8 sigma of the pairwise error: points with
// (a1-a2) <= 0.02 get exact fp32 rescan; others argmin-correct w.p. ~1-1e-9.
constexpr float FLAG_HALF = 0.02f;

constexpr int LDS_EPOS = 65536;                  // after 64KB E-fp16 fragments
constexpr int LDS_RED  = LDS_EPOS + 2048;
constexpr int LDS_TOT  = LDS_RED + 64;           // 67648 B -> 2 blocks/CU

constexpr int WL_OFF = 69632;                    // worklist byte offset in ws

typedef __attribute__((ext_vector_type(8))) _Float16 half8;
typedef __attribute__((ext_vector_type(4))) float    f32x4;

static __device__ __forceinline__ short f2h(float x) {   // RNE fp32->fp16
    _Float16 h = (_Float16)x;
    return __builtin_bit_cast(short, h);
}

// ---- K1: prep — pack E-fp16 fragment stream (64KB) + eposneg ---------------
__global__ __launch_bounds__(256) void vq_prep(const float* __restrict__ emb,
                                               short* __restrict__ EF,
                                               float* __restrict__ eposneg) {
    int q = blockIdx.x * 256 + threadIdx.x;
    if (q < 4096) {
        int kt = q >> 7, c = (q >> 6) & 1, lane = q & 63;
        int code = kt * 16 + (lane & 15);
        int d0   = c * 32 + (lane >> 4) * 8;
        const float* e = emb + (size_t)code * Dc + d0;
        short v[8];
#pragma unroll
        for (int j = 0; j < 8; ++j) v[j] = f2h(e[j]);
        *reinterpret_cast<int4*>(EF + (size_t)q * 8) = *reinterpret_cast<int4*>(v);
    } else if (q < 4096 + Kc) {
        int k = q - 4096;
        const float* e = emb + (size_t)k * Dc;
        float s0 = 0.f, s1 = 0.f, s2 = 0.f, s3 = 0.f;
#pragma unroll
        for (int d = 0; d < 16; ++d) {
            float v0 = e[d], v1 = e[16 + d], v2 = e[32 + d], v3 = e[48 + d];
            s0 = fmaf(v0, v0, s0); s1 = fmaf(v1, v1, s1);
            s2 = fmaf(v2, v2, s2); s3 = fmaf(v3, v3, s3);
        }
        eposneg[k] = -0.5f * ((s0 + s1) + (s2 + s3));
    }
}

// ---- K2: main (byte-identical to R12) --------------------------------------
// 512 blocks x 1024 thr; 66KB LDS -> 2 blocks/CU -> 8 waves/SIMD. Wave owns
// 32 points (2 MFMA tiles). Per kt: 2 ds_read + 4 MFMA (depth-2) + argmax.
__global__ __launch_bounds__(1024)
void vq_main(const float* __restrict__ z_e, const float* __restrict__ emb,
             const short* __restrict__ EF, const float* __restrict__ eposneg,
             float* __restrict__ out, float* __restrict__ acc,
             unsigned int* __restrict__ cnt, unsigned int* __restrict__ wl,
             unsigned int wcap) {
    extern __shared__ __align__(16) char smem[];
    const int tid = threadIdx.x;

    // stage 64 KB E-fp16 fragments + 2 KB eposneg
    {
        const int4* src = reinterpret_cast<const int4*>(EF);
        int4*       dst = reinterpret_cast<int4*>(smem);
#pragma unroll
        for (int i = 0; i < 4; ++i) dst[tid + i * 1024] = src[tid + i * 1024];
        if (tid < Kc) ((float*)(smem + LDS_EPOS))[tid] = eposneg[tid];
    }
    __syncthreads();
    const float* eposL = (const float*)(smem + LDS_EPOS);

    const int wave = tid >> 6, lane = tid & 63;
    const int p16 = lane & 15, g = lane >> 4;
    const int g4 = g * 4, lane16 = lane * 16;
    const int pbase = blockIdx.x * 512 + wave * 32;      // 32 points per wave
    const int b = pbase >> 12, hw0 = pbase & 4095;
    const float* zbase = z_e + (size_t)b * (Dc * HWc) + hw0;

    // Z fp16 fragments: element j -> Z[d = c*32+g*8+j][point = t*16+p16]
    half8 zh[2][2];
#pragma unroll
    for (int t = 0; t < 2; ++t)
#pragma unroll
        for (int c = 0; c < 2; ++c)
#pragma unroll
            for (int j = 0; j < 8; ++j)
                zh[t][c][j] = (_Float16)zbase[(size_t)(c * 32 + g * 8 + j) * HWc + t * 16 + p16];

    float a1[2] = {-3.4e38f, -3.4e38f}, a2[2] = {-3.4e38f, -3.4e38f};
    int   i1[2] = {0, 0};

#pragma unroll 1
    for (int kt = 0; kt < Kc / 16; ++kt) {
        const char* eb = smem + kt * 2048 + lane16;
        half8 eh0 = *reinterpret_cast<const half8*>(eb);
        half8 eh1 = *reinterpret_cast<const half8*>(eb + 1024);
        f32x4 en = *reinterpret_cast<const f32x4*>(eposL + kt * 16 + g4);
        f32x4 c0, c1;
        c0 = __builtin_amdgcn_mfma_f32_16x16x32_f16(eh0, zh[0][0], en, 0, 0, 0);
        c1 = __builtin_amdgcn_mfma_f32_16x16x32_f16(eh0, zh[1][0], en, 0, 0, 0);
        c0 = __builtin_amdgcn_mfma_f32_16x16x32_f16(eh1, zh[0][1], c0, 0, 0, 0);
        c1 = __builtin_amdgcn_mfma_f32_16x16x32_f16(eh1, zh[1][1], c1, 0, 0, 0);
#pragma unroll
        for (int r = 0; r < 4; ++r) {                    // code ascending in r
            float s0 = c0[r], s1 = c1[r];
            int code = kt * 16 + g4 + r;
            bool gt0 = s0 > a1[0];                       // strict: first-occurrence
            a2[0] = fmaxf(gt0 ? a1[0] : s0, a2[0]);
            i1[0] = gt0 ? code : i1[0];
            a1[0] = gt0 ? s0 : a1[0];
            bool gt1 = s1 > a1[1];
            a2[1] = fmaxf(gt1 ? a1[1] : s1, a2[1]);
            i1[1] = gt1 ? code : i1[1];
            a1[1] = gt1 ? s1 : a1[1];
        }
    }

    // merge (a1,i1,a2) across the 4 lane-groups (code subsets), per point
#pragma unroll
    for (int off = 16; off <= 32; off <<= 1)
#pragma unroll
        for (int t = 0; t < 2; ++t) {
            float oa1 = __shfl_xor(a1[t], off, 64);
            float oa2 = __shfl_xor(a2[t], off, 64);
            int   oi1 = __shfl_xor(i1[t], off, 64);
            float lo  = fminf(a1[t], oa1);
            a2[t] = fmaxf(fmaxf(a2[t], oa2), lo);
            bool take = (oa1 > a1[t]) || (oa1 == a1[t] && oi1 < i1[t]);
            a1[t] = take ? oa1 : a1[t];
            i1[t] = take ? oi1 : i1[t];
        }

    // worklist append (wave-aggregated): bit l of mask -> point pbase+l flagged
    unsigned m[2];
#pragma unroll
    for (int t = 0; t < 2; ++t) {
        bool flg = (a1[t] - a2[t]) <= FLAG_HALF;         // near-tie in approx metric
        m[t] = (unsigned)(__ballot(g == 0 && flg) & 0xFFFFull);
    }
    unsigned mask = m[0] | (m[1] << 16);
    int npts = __popc(mask);
    unsigned wbase = 0;
    if (lane == 0 && npts) wbase = atomicAdd(cnt, (unsigned)npts);
    wbase = __shfl(wbase, 0, 64);
    if (lane < 32 && ((mask >> lane) & 1u)) {
        unsigned pos = wbase + __popc(mask & ((1u << lane) - 1u));
        if (pos < wcap) wl[pos] = (unsigned)(pbase + lane);
    }

    // epilogue: gather exact fp32 code rows, write z_q, loss from zh
    // (fp16 zh in loss: bias ~ 3e-8, negligible vs 8.75e-2 threshold)
    float lsum = 0.f;
#pragma unroll
    for (int t = 0; t < 2; ++t) {
        const float* er = emb + (size_t)i1[t] * Dc;
        float* op = out + (size_t)b * (Dc * HWc) + hw0 + t * 16 + p16;
#pragma unroll
        for (int c = 0; c < 2; ++c)
#pragma unroll
            for (int j = 0; j < 8; ++j) {
                int d = c * 32 + g * 8 + j;              // lane's own d-slots
                float e = er[d];
                op[(size_t)d * HWc] = e;
                float f = e - (float)zh[t][c][j];
                lsum = fmaf(f, f, lsum);
            }
    }

    // block-level loss reduction -> one atomic per block
    float v = lsum;
#pragma unroll
    for (int off = 32; off > 0; off >>= 1) v += __shfl_down(v, off);
    float* red = (float*)(smem + LDS_RED);
    if (lane == 0) red[wave] = v;
    __syncthreads();
    if (tid == 0) {
        float bs = 0.f;
#pragma unroll
        for (int w = 0; w < 16; ++w) bs += red[w];
        atomicAdd(acc, bs);
    }
}

// ---- K3: exact fp32 fixup — 4 points per wave share one codebook stream ----
// Each e-row chunk is loaded ONCE and consumed by 4 points (4x less L2
// traffic). Per-point accumulation order is EXACTLY R1/R11's proven order
// (same bits, same decisions). Padding slots duplicate the last point and are
// masked off at writeback.
__global__ __launch_bounds__(256) void vq_fixup(const float* __restrict__ z_e,
                                                const float* __restrict__ emb,
                                                const float* __restrict__ eposneg,
                                                const unsigned int* __restrict__ wl,
                                                const unsigned int* __restrict__ cnt,
                                                unsigned int wcap,
                                                float* __restrict__ out,
                                                float* __restrict__ acc) {
    __shared__ __align__(16) float zsh[4][4][64];        // [wave][slot][dim]
    const unsigned n = min(*cnt, wcap);
    const int lane = threadIdx.x & 63;
    const int wv   = threadIdx.x >> 6;
    const unsigned wid = (blockIdx.x * 256 + threadIdx.x) >> 6;
    const unsigned nw  = (gridDim.x * 256) >> 6;
    const unsigned nch = (n + 3) >> 2;                   // chunks of 4 points
    for (unsigned ch = wid; ch < nch; ch += nw) {
        const unsigned base = ch * 4;
        int pp[4];
#pragma unroll
        for (int s = 0; s < 4; ++s) {
            unsigned idx = base + (unsigned)s;
            pp[s] = (int)wl[idx < n ? idx : (n - 1)];    // pad: dup last point
            int b = pp[s] >> 12, hw = pp[s] & 4095;
            zsh[wv][s][lane] = z_e[(size_t)b * (Dc * HWc) + (size_t)lane * HWc + hw];
        }
        asm volatile("s_waitcnt lgkmcnt(0)" ::: "memory");  // cross-lane LDS dep

        float bd[4] = {3.4e38f, 3.4e38f, 3.4e38f, 3.4e38f};
        int   bi[4] = {0, 0, 0, 0};
#pragma unroll 1
        for (int r = 0; r < 8; ++r) {                    // codes r*64 + lane
            const int code = r * 64 + lane;
            const float4* er4 = reinterpret_cast<const float4*>(emb + (size_t)code * Dc);
            float s0[4] = {0.f, 0.f, 0.f, 0.f}, s1[4] = {0.f, 0.f, 0.f, 0.f};
            float s2[4] = {0.f, 0.f, 0.f, 0.f}, s3[4] = {0.f, 0.f, 0.f, 0.f};
#pragma unroll
            for (int q = 0; q < 4; ++q) {                // d order 0..15 per chain
                float4 e0 = er4[q], e1 = er4[4 + q], e2 = er4[8 + q], e3 = er4[12 + q];
#pragma unroll
                for (int s = 0; s < 4; ++s) {            // 4 points share the e row
                    const float4* z4 = reinterpret_cast<const float4*>(zsh[wv][s]);
                    float4 zz0 = z4[q],      zz1 = z4[4 + q];
                    float4 zz2 = z4[8 + q],  zz3 = z4[12 + q];
                    s0[s] = fmaf(e0.x, zz0.x, s0[s]); s0[s] = fmaf(e0.y, zz0.y, s0[s]);
                    s0[s] = fmaf(e0.z, zz0.z, s0[s]); s0[s] = fmaf(e0.w, zz0.w, s0[s]);
                    s1[s] = fmaf(e1.x, zz1.x, s1[s]); s1[s] = fmaf(e1.y, zz1.y, s1[s]);
                    s1[s] = fmaf(e1.z, zz1.z, s1[s]); s1[s] = fmaf(e1.w, zz1.w, s1[s]);
                    s2[s] = fmaf(e2.x, zz2.x, s2[s]); s2[s] = fmaf(e2.y, zz2.y, s2[s]);
                    s2[s] = fmaf(e2.z, zz2.z, s2[s]); s2[s] = fmaf(e2.w, zz2.w, s2[s]);
                    s3[s] = fmaf(e3.x, zz3.x, s3[s]); s3[s] = fmaf(e3.y, zz3.y, s3[s]);
                    s3[s] = fmaf(e3.z, zz3.z, s3[s]); s3[s] = fmaf(e3.w, zz3.w, s3[s]);
                }
            }
            const float en2 = -2.0f * eposneg[code];     // +||e||^2 term
#pragma unroll
            for (int s = 0; s < 4; ++s) {
                float dot  = (s0[s] + s1[s]) + (s2[s] + s3[s]);
                float dist = fmaf(-2.0f, dot, en2);
                bool lt = dist < bd[s];                  // within-lane ascending
                bd[s] = lt ? dist : bd[s];
                bi[s] = lt ? code : bi[s];
            }
        }
        // per-slot cross-lane argmin + patch (skip padding slots)
#pragma unroll 1
        for (int s = 0; s < 4; ++s) {
            if (base + (unsigned)s >= n) break;
            float bds = bd[s]; int bis = bi[s];
#pragma unroll
            for (int off = 32; off > 0; off >>= 1) {
                float od = __shfl_xor(bds, off, 64);
                int   oi = __shfl_xor(bis, off, 64);
                bool take = (od < bds) || (od == bds && oi < bis);
                bds = take ? od : bds;
                bis = take ? oi : bis;
            }
            int p = pp[s];
            int b = p >> 12, hw = p & 4095;
            float* op = out + (size_t)b * (Dc * HWc) + (size_t)lane * HWc + hw;
            float eo = *op;
            float en = emb[(size_t)bis * Dc + lane];
            float zf = zsh[wv][s][lane];
            float dn = en - zf, dold = eo - zf;
            float delta = fmaf(dn, dn, -dold * dold);
            *op = en;
#pragma unroll
            for (int off = 32; off > 0; off >>= 1) delta += __shfl_down(delta, off);
            if (lane == 0) atomicAdd(acc, delta);
        }
    }
}

// ---- K4: finalize loss -----------------------------------------------------
__global__ void vq_finalize(const float* __restrict__ acc, float* __restrict__ out_loss) {
    out_loss[0] = 1.25f * (acc[0] * INV_ELEMS);
}

extern "C" void kernel_launch(void* const* d_in, const int* in_sizes, int n_in,
                              void* d_out, int out_size, void* d_ws, size_t ws_size,
                              hipStream_t stream) {
    const float* z_e = (const float*)d_in[0];
    const float* emb = (const float*)d_in[1];
    float* out = (float*)d_out;

    char* ws = (char*)d_ws;
    float*    acc     = (float*)(ws);                 // 4 B
    unsigned* cnt     = (unsigned*)(ws + 4);          // 4 B worklist counter
    float*    eposneg = (float*)(ws + 256);           // 512 f32 = 2 KB
    short*    EF      = (short*)(ws + 4096);          // 64 KB fp16 fragment stream
    unsigned* wl      = (unsigned*)(ws + WL_OFF);     // worklist (rest of ws)

    unsigned wcap = 0;
    if (ws_size > (size_t)WL_OFF + 4)
        wcap = (unsigned)min((size_t)Nc, (ws_size - WL_OFF) / 4);

    hipFuncSetAttribute(reinterpret_cast<const void*>(vq_main),
                        hipFuncAttributeMaxDynamicSharedMemorySize, LDS_TOT);

    hipMemsetAsync(ws, 0, 8, stream);                 // acc + cnt
    vq_prep<<<18, 256, 0, stream>>>(emb, EF, eposneg);
    vq_main<<<Nc / 512, 1024, LDS_TOT, stream>>>(z_e, emb, EF, eposneg, out, acc,
                                                 cnt, wl, wcap);
    vq_fixup<<<1024, 256, 0, stream>>>(z_e, emb, eposneg, wl, cnt, wcap, out, acc);
    vq_finalize<<<1, 1, 0, stream>>>(acc, out + (size_t)Nc * Dc);
}

// Round 14
// 107.687 us; speedup vs baseline: 2.8691x; 1.0708x over previous
//
#include <hip/hip_runtime.h>

// z_e: [B=64, D=64, H=64, W=64] fp32 ; embeddings: [K=512, D=64] fp32
// out: z_q_st [64,64,64,64] fp32 ++ loss (1 fp32)
constexpr int Dc  = 64;
constexpr int Kc  = 512;
constexpr int HWc = 4096;
constexpr int Nc  = 64 * HWc;                    // 262144 points
constexpr float INV_ELEMS = 1.0f / 16777216.0f;
// fp16 1-term metric: s = eh.zh - ||e||^2/2. sigma_s ~ 1.8e-3 (fp16 conv err,
// 64-dim CLT). FLAG_HALF = 0.02 ~ 7.8 sigma of the pairwise error: points with
// (a1-a2) <= 0.02 get exact fp32 rescan; others argmin-correct w.p. ~1-1e-9.
// Measured flag rate ~1.5% (R13 FETCH arithmetic).
constexpr float FLAG_HALF = 0.02f;

constexpr int LDS_EPOS = 65536;                  // vq_main: after 64KB E-fp16
constexpr int LDS_RED  = LDS_EPOS + 2048;
constexpr int LDS_TOT  = LDS_RED + 64;           // 67648 B -> 2 blocks/CU

constexpr int FX_EPOS  = 131072;                 // vq_fixup: after 128KB E-fp32
constexpr int FX_TOT   = FX_EPOS + 2048;         // 133120 B -> 1 block/CU

constexpr int WL_OFF = 69632;                    // worklist byte offset in ws

typedef __attribute__((ext_vector_type(8))) _Float16 half8;
typedef __attribute__((ext_vector_type(4))) float    f32x4;

static __device__ __forceinline__ short f2h(float x) {   // RNE fp32->fp16
    _Float16 h = (_Float16)x;
    return __builtin_bit_cast(short, h);
}

// ---- K1: prep — pack E-fp16 fragment stream (64KB) + eposneg ---------------
__global__ __launch_bounds__(256) void vq_prep(const float* __restrict__ emb,
                                               short* __restrict__ EF,
                                               float* __restrict__ eposneg) {
    int q = blockIdx.x * 256 + threadIdx.x;
    if (q < 4096) {
        int kt = q >> 7, c = (q >> 6) & 1, lane = q & 63;
        int code = kt * 16 + (lane & 15);
        int d0   = c * 32 + (lane >> 4) * 8;
        const float* e = emb + (size_t)code * Dc + d0;
        short v[8];
#pragma unroll
        for (int j = 0; j < 8; ++j) v[j] = f2h(e[j]);
        *reinterpret_cast<int4*>(EF + (size_t)q * 8) = *reinterpret_cast<int4*>(v);
    } else if (q < 4096 + Kc) {
        int k = q - 4096;
        const float* e = emb + (size_t)k * Dc;
        float s0 = 0.f, s1 = 0.f, s2 = 0.f, s3 = 0.f;
#pragma unroll
        for (int d = 0; d < 16; ++d) {
            float v0 = e[d], v1 = e[16 + d], v2 = e[32 + d], v3 = e[48 + d];
            s0 = fmaf(v0, v0, s0); s1 = fmaf(v1, v1, s1);
            s2 = fmaf(v2, v2, s2); s3 = fmaf(v3, v3, s3);
        }
        eposneg[k] = -0.5f * ((s0 + s1) + (s2 + s3));
    }
}

// ---- K2: main (R13 structure; a2 update via fmed3 — bit-identical) ---------
// 512 blocks x 1024 thr; 66KB LDS -> 2 blocks/CU -> 8 waves/SIMD. Wave owns
// 32 points (2 MFMA tiles). Per kt: 2 ds_read + 4 MFMA (depth-2) + argmax.
__global__ __launch_bounds__(1024)
void vq_main(const float* __restrict__ z_e, const float* __restrict__ emb,
             const short* __restrict__ EF, const float* __restrict__ eposneg,
             float* __restrict__ out, float* __restrict__ acc,
             unsigned int* __restrict__ cnt, unsigned int* __restrict__ wl,
             unsigned int wcap) {
    extern __shared__ __align__(16) char smem[];
    const int tid = threadIdx.x;

    // stage 64 KB E-fp16 fragments + 2 KB eposneg
    {
        const int4* src = reinterpret_cast<const int4*>(EF);
        int4*       dst = reinterpret_cast<int4*>(smem);
#pragma unroll
        for (int i = 0; i < 4; ++i) dst[tid + i * 1024] = src[tid + i * 1024];
        if (tid < Kc) ((float*)(smem + LDS_EPOS))[tid] = eposneg[tid];
    }
    __syncthreads();
    const float* eposL = (const float*)(smem + LDS_EPOS);

    const int wave = tid >> 6, lane = tid & 63;
    const int p16 = lane & 15, g = lane >> 4;
    const int g4 = g * 4, lane16 = lane * 16;
    const int pbase = blockIdx.x * 512 + wave * 32;      // 32 points per wave
    const int b = pbase >> 12, hw0 = pbase & 4095;
    const float* zbase = z_e + (size_t)b * (Dc * HWc) + hw0;

    // Z fp16 fragments: element j -> Z[d = c*32+g*8+j][point = t*16+p16]
    half8 zh[2][2];
#pragma unroll
    for (int t = 0; t < 2; ++t)
#pragma unroll
        for (int c = 0; c < 2; ++c)
#pragma unroll
            for (int j = 0; j < 8; ++j)
                zh[t][c][j] = (_Float16)zbase[(size_t)(c * 32 + g * 8 + j) * HWc + t * 16 + p16];

    float a1[2] = {-3.4e38f, -3.4e38f}, a2[2] = {-3.4e38f, -3.4e38f};
    int   i1[2] = {0, 0};

#pragma unroll 1
    for (int kt = 0; kt < Kc / 16; ++kt) {
        const char* eb = smem + kt * 2048 + lane16;
        half8 eh0 = *reinterpret_cast<const half8*>(eb);
        half8 eh1 = *reinterpret_cast<const half8*>(eb + 1024);
        f32x4 en = *reinterpret_cast<const f32x4*>(eposL + kt * 16 + g4);
        f32x4 c0, c1;
        c0 = __builtin_amdgcn_mfma_f32_16x16x32_f16(eh0, zh[0][0], en, 0, 0, 0);
        c1 = __builtin_amdgcn_mfma_f32_16x16x32_f16(eh0, zh[1][0], en, 0, 0, 0);
        c0 = __builtin_amdgcn_mfma_f32_16x16x32_f16(eh1, zh[0][1], c0, 0, 0, 0);
        c1 = __builtin_amdgcn_mfma_f32_16x16x32_f16(eh1, zh[1][1], c1, 0, 0, 0);
#pragma unroll
        for (int r = 0; r < 4; ++r) {                    // code ascending in r
            float s0 = c0[r], s1 = c1[r];
            int code = kt * 16 + g4 + r;
            // a2 <= a1 invariant => med3(a2, s, a1_old) == old fmax(sel, a2)
            bool gt0 = s0 > a1[0];                       // strict: first-occurrence
            a2[0] = __builtin_amdgcn_fmed3f(a2[0], s0, a1[0]);
            i1[0] = gt0 ? code : i1[0];
            a1[0] = gt0 ? s0 : a1[0];
            bool gt1 = s1 > a1[1];
            a2[1] = __builtin_amdgcn_fmed3f(a2[1], s1, a1[1]);
            i1[1] = gt1 ? code : i1[1];
            a1[1] = gt1 ? s1 : a1[1];
        }
    }

    // merge (a1,i1,a2) across the 4 lane-groups (code subsets), per point
#pragma unroll
    for (int off = 16; off <= 32; off <<= 1)
#pragma unroll
        for (int t = 0; t < 2; ++t) {
            float oa1 = __shfl_xor(a1[t], off, 64);
            float oa2 = __shfl_xor(a2[t], off, 64);
            int   oi1 = __shfl_xor(i1[t], off, 64);
            float lo  = fminf(a1[t], oa1);
            a2[t] = fmaxf(fmaxf(a2[t], oa2), lo);
            bool take = (oa1 > a1[t]) || (oa1 == a1[t] && oi1 < i1[t]);
            a1[t] = take ? oa1 : a1[t];
            i1[t] = take ? oi1 : i1[t];
        }

    // worklist append (wave-aggregated): bit l of mask -> point pbase+l flagged
    unsigned m[2];
#pragma unroll
    for (int t = 0; t < 2; ++t) {
        bool flg = (a1[t] - a2[t]) <= FLAG_HALF;         // near-tie in approx metric
        m[t] = (unsigned)(__ballot(g == 0 && flg) & 0xFFFFull);
    }
    unsigned mask = m[0] | (m[1] << 16);
    int npts = __popc(mask);
    unsigned wbase = 0;
    if (lane == 0 && npts) wbase = atomicAdd(cnt, (unsigned)npts);
    wbase = __shfl(wbase, 0, 64);
    if (lane < 32 && ((mask >> lane) & 1u)) {
        unsigned pos = wbase + __popc(mask & ((1u << lane) - 1u));
        if (pos < wcap) wl[pos] = (unsigned)(pbase + lane);
    }

    // epilogue: gather exact fp32 code rows, write z_q, loss from zh
    float lsum = 0.f;
#pragma unroll
    for (int t = 0; t < 2; ++t) {
        const float* er = emb + (size_t)i1[t] * Dc;
        float* op = out + (size_t)b * (Dc * HWc) + hw0 + t * 16 + p16;
#pragma unroll
        for (int c = 0; c < 2; ++c)
#pragma unroll
            for (int j = 0; j < 8; ++j) {
                int d = c * 32 + g * 8 + j;              // lane's own d-slots
                float e = er[d];
                op[(size_t)d * HWc] = e;
                float f = e - (float)zh[t][c][j];
                lsum = fmaf(f, f, lsum);
            }
    }

    // block-level loss reduction -> one atomic per block
    float v = lsum;
#pragma unroll
    for (int off = 32; off > 0; off >>= 1) v += __shfl_down(v, off);
    float* red = (float*)(smem + LDS_RED);
    if (lane == 0) red[wave] = v;
    __syncthreads();
    if (tid == 0) {
        float bs = 0.f;
#pragma unroll
        for (int w = 0; w < 16; ++w) bs += red[w];
        atomicAdd(acc, bs);
    }
}

// ---- K3: exact fp32 fixup — LDS codebook (XOR-swizzled), 4 pts/wave --------
// Chunk q of row r stored at slot (q ^ (r&15)) within the row's 256B: read
// instructions then spread 64 lanes across all 32 banks (8/bank = b128 floor)
// instead of 16-way conflicts. Values bit-identical to global; accumulation
// order EXACTLY R1/R13's proven order -> same decisions.
__global__ __launch_bounds__(256) void vq_fixup(const float* __restrict__ z_e,
                                                const float* __restrict__ emb,
                                                const float* __restrict__ eposneg,
                                                const unsigned int* __restrict__ wl,
                                                const unsigned int* __restrict__ cnt,
                                                unsigned int wcap,
                                                float* __restrict__ out,
                                                float* __restrict__ acc) {
    extern __shared__ __align__(16) char fsm[];          // 128KB E-fp32 + 2KB epos
    __shared__ __align__(16) float zsh[4][4][64];        // [wave][slot][dim]
    const unsigned n = min(*cnt, wcap);
    const unsigned nch = (n + 3) >> 2;                   // chunks of 4 points
    if (blockIdx.x * 4 >= nch) return;                   // no work: skip staging

    // stage codebook (swizzled) + eposneg
    {
        const float4* e4 = reinterpret_cast<const float4*>(emb);
        for (int i = threadIdx.x; i < 8192; i += 256) {
            int row = i >> 4, q = i & 15;
            *reinterpret_cast<float4*>(fsm + row * 256 + ((q ^ (row & 15)) << 4)) = e4[i];
        }
        for (int i = threadIdx.x; i < Kc; i += 256)
            ((float*)(fsm + FX_EPOS))[i] = eposneg[i];
    }
    __syncthreads();
    const float* eposL = (const float*)(fsm + FX_EPOS);

    const int lane = threadIdx.x & 63;
    const int wv   = threadIdx.x >> 6;
    const int swz16 = (lane & 15) << 4;                  // code&15 == lane&15
    const unsigned wid = blockIdx.x * 4 + wv;
    const unsigned nw  = gridDim.x * 4;
    for (unsigned ch = wid; ch < nch; ch += nw) {
        const unsigned base = ch * 4;
        int pp[4];
#pragma unroll
        for (int s = 0; s < 4; ++s) {
            unsigned idx = base + (unsigned)s;
            pp[s] = (int)wl[idx < n ? idx : (n - 1)];    // pad: dup last point
            int b = pp[s] >> 12, hw = pp[s] & 4095;
            zsh[wv][s][lane] = z_e[(size_t)b * (Dc * HWc) + (size_t)lane * HWc + hw];
        }
        asm volatile("s_waitcnt lgkmcnt(0) vmcnt(0)" ::: "memory");

        float bd[4] = {3.4e38f, 3.4e38f, 3.4e38f, 3.4e38f};
        int   bi[4] = {0, 0, 0, 0};
#pragma unroll 1
        for (int r = 0; r < 8; ++r) {                    // codes r*64 + lane
            const int code = r * 64 + lane;
            const uintptr_t ebp = (uintptr_t)fsm + (unsigned)code * 256;
            float s0[4] = {0.f, 0.f, 0.f, 0.f}, s1[4] = {0.f, 0.f, 0.f, 0.f};
            float s2[4] = {0.f, 0.f, 0.f, 0.f}, s3[4] = {0.f, 0.f, 0.f, 0.f};
#pragma unroll
            for (int q = 0; q < 4; ++q) {                // d order 0..15 per chain
                float4 e0 = *reinterpret_cast<const float4*>(ebp + ((( q      << 4)) ^ swz16));
                float4 e1 = *reinterpret_cast<const float4*>(ebp + ((((4 + q) << 4)) ^ swz16));
                float4 e2 = *reinterpret_cast<const float4*>(ebp + ((((8 + q) << 4)) ^ swz16));
                float4 e3 = *reinterpret_cast<const float4*>(ebp + ((((12 + q) << 4)) ^ swz16));
#pragma unroll
                for (int s = 0; s < 4; ++s) {            // 4 points share the e row
                    const float4* z4 = reinterpret_cast<const float4*>(zsh[wv][s]);
                    float4 zz0 = z4[q],      zz1 = z4[4 + q];
                    float4 zz2 = z4[8 + q],  zz3 = z4[12 + q];
                    s0[s] = fmaf(e0.x, zz0.x, s0[s]); s0[s] = fmaf(e0.y, zz0.y, s0[s]);
                    s0[s] = fmaf(e0.z, zz0.z, s0[s]); s0[s] = fmaf(e0.w, zz0.w, s0[s]);
                    s1[s] = fmaf(e1.x, zz1.x, s1[s]); s1[s] = fmaf(e1.y, zz1.y, s1[s]);
                    s1[s] = fmaf(e1.z, zz1.z, s1[s]); s1[s] = fmaf(e1.w, zz1.w, s1[s]);
                    s2[s] = fmaf(e2.x, zz2.x, s2[s]); s2[s] = fmaf(e2.y, zz2.y, s2[s]);
                    s2[s] = fmaf(e2.z, zz2.z, s2[s]); s2[s] = fmaf(e2.w, zz2.w, s2[s]);
                    s3[s] = fmaf(e3.x, zz3.x, s3[s]); s3[s] = fmaf(e3.y, zz3.y, s3[s]);
                    s3[s] = fmaf(e3.z, zz3.z, s3[s]); s3[s] = fmaf(e3.w, zz3.w, s3[s]);
                }
            }
            const float en2 = -2.0f * eposL[code];       // +||e||^2 term
#pragma unroll
            for (int s = 0; s < 4; ++s) {
                float dot  = (s0[s] + s1[s]) + (s2[s] + s3[s]);
                float dist = fmaf(-2.0f, dot, en2);
                bool lt = dist < bd[s];                  // within-lane ascending
                bd[s] = lt ? dist : bd[s];
                bi[s] = lt ? code : bi[s];
            }
        }
        // per-slot cross-lane argmin + patch (skip padding slots)
#pragma unroll 1
        for (int s = 0; s < 4; ++s) {
            if (base + (unsigned)s >= n) break;
            float bds = bd[s]; int bis = bi[s];
#pragma unroll
            for (int off = 32; off > 0; off >>= 1) {
                float od = __shfl_xor(bds, off, 64);
                int   oi = __shfl_xor(bis, off, 64);
                bool take = (od < bds) || (od == bds && oi < bis);
                bds = take ? od : bds;
                bis = take ? oi : bis;
            }
            int p = pp[s];
            int b = p >> 12, hw = p & 4095;
            float* op = out + (size_t)b * (Dc * HWc) + (size_t)lane * HWc + hw;
            float eo = *op;
            float en = emb[(size_t)bis * Dc + lane];
            float zf = zsh[wv][s][lane];
            float dn = en - zf, dold = eo - zf;
            float delta = fmaf(dn, dn, -dold * dold);
            *op = en;
#pragma unroll
            for (int off = 32; off > 0; off >>= 1) delta += __shfl_down(delta, off);
            if (lane == 0) atomicAdd(acc, delta);
        }
    }
}

// ---- K4: finalize loss -----------------------------------------------------
__global__ void vq_finalize(const float* __restrict__ acc, float* __restrict__ out_loss) {
    out_loss[0] = 1.25f * (acc[0] * INV_ELEMS);
}

extern "C" void kernel_launch(void* const* d_in, const int* in_sizes, int n_in,
                              void* d_out, int out_size, void* d_ws, size_t ws_size,
                              hipStream_t stream) {
    const float* z_e = (const float*)d_in[0];
    const float* emb = (const float*)d_in[1];
    float* out = (float*)d_out;

    char* ws = (char*)d_ws;
    float*    acc     = (float*)(ws);                 // 4 B
    unsigned* cnt     = (unsigned*)(ws + 4);          // 4 B worklist counter
    float*    eposneg = (float*)(ws + 256);           // 512 f32 = 2 KB
    short*    EF      = (short*)(ws + 4096);          // 64 KB fp16 fragment stream
    unsigned* wl      = (unsigned*)(ws + WL_OFF);     // worklist (rest of ws)

    unsigned wcap = 0;
    if (ws_size > (size_t)WL_OFF + 4)
        wcap = (unsigned)min((size_t)Nc, (ws_size - WL_OFF) / 4);

    hipFuncSetAttribute(reinterpret_cast<const void*>(vq_main),
                        hipFuncAttributeMaxDynamicSharedMemorySize, LDS_TOT);
    hipFuncSetAttribute(reinterpret_cast<const void*>(vq_fixup),
                        hipFuncAttributeMaxDynamicSharedMemorySize, FX_TOT);

    hipMemsetAsync(ws, 0, 8, stream);                 // acc + cnt
    vq_prep<<<18, 256, 0, stream>>>(emb, EF, eposneg);
    vq_main<<<Nc / 512, 1024, LDS_TOT, stream>>>(z_e, emb, EF, eposneg, out, acc,
                                                 cnt, wl, wcap);
    vq_fixup<<<256, 256, FX_TOT, stream>>>(z_e, emb, eposneg, wl, cnt, wcap, out, acc);
    vq_finalize<<<1, 1, 0, stream>>>(acc, out + (size_t)Nc * Dc);
}

// Round 15
// 81.788 us; speedup vs baseline: 3.7776x; 1.3167x over previous
//
#include <hip/hip_runtime.h>

// z_e: [B=64, D=64, H=64, W=64] fp32 ; embeddings: [K=512, D=64] fp32
// out: z_q_st [64,64,64,64] fp32 ++ loss (1 fp32)
constexpr int Dc  = 64;
constexpr int Kc  = 512;
constexpr int HWc = 4096;
constexpr int Nc  = 64 * HWc;                    // 262144 points
constexpr float INV_ELEMS = 1.0f / 16777216.0f;
// fp16 1-term metric: s = eh.zh - ||e||^2/2. sigma_s ~ 1.8e-3. FLAG_HALF =
// 0.02 ~ 7.8 sigma pairwise: points with (a1-a2) <= 0.02 get exact fp32
// rescan. Measured flag rate ~1.5% (n ~ 3.9K).
constexpr float FLAG_HALF = 0.02f;

constexpr int LDS_EPOS = 65536;                  // vq_main: after 64KB E-fp16
constexpr int LDS_RED  = LDS_EPOS + 2048;
constexpr int LDS_TOT  = LDS_RED + 64;           // 67648 B -> 2 blocks/CU

constexpr int FX_EPOS  = 131072;                 // vq_fixup: after 128KB E-fp32
constexpr int FX_TOT   = FX_EPOS + 2048;         // 133120 B -> 1 block/CU

constexpr int WL_H_OFF = 69632;                  // headers: {oldidx, point} u64
constexpr int WL_Z_OFF = WL_H_OFF + 262144;      // stashed z: 64 f32 per entry

typedef __attribute__((ext_vector_type(8))) _Float16 half8;
typedef __attribute__((ext_vector_type(4))) float    f32x4;

static __device__ __forceinline__ short f2h(float x) {   // RNE fp32->fp16
    _Float16 h = (_Float16)x;
    return __builtin_bit_cast(short, h);
}

// ---- K1: prep — pack E-fp16 fragment stream (64KB) + eposneg ---------------
__global__ __launch_bounds__(256) void vq_prep(const float* __restrict__ emb,
                                               short* __restrict__ EF,
                                               float* __restrict__ eposneg) {
    int q = blockIdx.x * 256 + threadIdx.x;
    if (q < 4096) {
        int kt = q >> 7, c = (q >> 6) & 1, lane = q & 63;
        int code = kt * 16 + (lane & 15);
        int d0   = c * 32 + (lane >> 4) * 8;
        const float* e = emb + (size_t)code * Dc + d0;
        short v[8];
#pragma unroll
        for (int j = 0; j < 8; ++j) v[j] = f2h(e[j]);
        *reinterpret_cast<int4*>(EF + (size_t)q * 8) = *reinterpret_cast<int4*>(v);
    } else if (q < 4096 + Kc) {
        int k = q - 4096;
        const float* e = emb + (size_t)k * Dc;
        float s0 = 0.f, s1 = 0.f, s2 = 0.f, s3 = 0.f;
#pragma unroll
        for (int d = 0; d < 16; ++d) {
            float v0 = e[d], v1 = e[16 + d], v2 = e[32 + d], v3 = e[48 + d];
            s0 = fmaf(v0, v0, s0); s1 = fmaf(v1, v1, s1);
            s2 = fmaf(v2, v2, s2); s3 = fmaf(v3, v3, s3);
        }
        eposneg[k] = -0.5f * ((s0 + s1) + (s2 + s3));
    }
}

// ---- K2: main (R14 structure; worklist now stashes z fp32 + old index) -----
__global__ __launch_bounds__(1024)
void vq_main(const float* __restrict__ z_e, const float* __restrict__ emb,
             const short* __restrict__ EF, const float* __restrict__ eposneg,
             float* __restrict__ out, float* __restrict__ acc,
             unsigned int* __restrict__ cnt,
             unsigned long long* __restrict__ wlh, float* __restrict__ wlz,
             unsigned int hcap, unsigned int zcap) {
    extern __shared__ __align__(16) char smem[];
    const int tid = threadIdx.x;

    // stage 64 KB E-fp16 fragments + 2 KB eposneg
    {
        const int4* src = reinterpret_cast<const int4*>(EF);
        int4*       dst = reinterpret_cast<int4*>(smem);
#pragma unroll
        for (int i = 0; i < 4; ++i) dst[tid + i * 1024] = src[tid + i * 1024];
        if (tid < Kc) ((float*)(smem + LDS_EPOS))[tid] = eposneg[tid];
    }
    __syncthreads();
    const float* eposL = (const float*)(smem + LDS_EPOS);

    const int wave = tid >> 6, lane = tid & 63;
    const int p16 = lane & 15, g = lane >> 4;
    const int g4 = g * 4, lane16 = lane * 16;
    const int pbase = blockIdx.x * 512 + wave * 32;      // 32 points per wave
    const int b = pbase >> 12, hw0 = pbase & 4095;
    const float* zbase = z_e + (size_t)b * (Dc * HWc) + hw0;

    // Z fp16 fragments: element j -> Z[d = c*32+g*8+j][point = t*16+p16]
    half8 zh[2][2];
#pragma unroll
    for (int t = 0; t < 2; ++t)
#pragma unroll
        for (int c = 0; c < 2; ++c)
#pragma unroll
            for (int j = 0; j < 8; ++j)
                zh[t][c][j] = (_Float16)zbase[(size_t)(c * 32 + g * 8 + j) * HWc + t * 16 + p16];

    float a1[2] = {-3.4e38f, -3.4e38f}, a2[2] = {-3.4e38f, -3.4e38f};
    int   i1[2] = {0, 0};

#pragma unroll 1
    for (int kt = 0; kt < Kc / 16; ++kt) {
        const char* eb = smem + kt * 2048 + lane16;
        half8 eh0 = *reinterpret_cast<const half8*>(eb);
        half8 eh1 = *reinterpret_cast<const half8*>(eb + 1024);
        f32x4 en = *reinterpret_cast<const f32x4*>(eposL + kt * 16 + g4);
        f32x4 c0, c1;
        c0 = __builtin_amdgcn_mfma_f32_16x16x32_f16(eh0, zh[0][0], en, 0, 0, 0);
        c1 = __builtin_amdgcn_mfma_f32_16x16x32_f16(eh0, zh[1][0], en, 0, 0, 0);
        c0 = __builtin_amdgcn_mfma_f32_16x16x32_f16(eh1, zh[0][1], c0, 0, 0, 0);
        c1 = __builtin_amdgcn_mfma_f32_16x16x32_f16(eh1, zh[1][1], c1, 0, 0, 0);
#pragma unroll
        for (int r = 0; r < 4; ++r) {                    // code ascending in r
            float s0 = c0[r], s1 = c1[r];
            int code = kt * 16 + g4 + r;
            bool gt0 = s0 > a1[0];                       // strict: first-occurrence
            a2[0] = __builtin_amdgcn_fmed3f(a2[0], s0, a1[0]);
            i1[0] = gt0 ? code : i1[0];
            a1[0] = gt0 ? s0 : a1[0];
            bool gt1 = s1 > a1[1];
            a2[1] = __builtin_amdgcn_fmed3f(a2[1], s1, a1[1]);
            i1[1] = gt1 ? code : i1[1];
            a1[1] = gt1 ? s1 : a1[1];
        }
    }

    // merge (a1,i1,a2) across the 4 lane-groups (code subsets), per point
#pragma unroll
    for (int off = 16; off <= 32; off <<= 1)
#pragma unroll
        for (int t = 0; t < 2; ++t) {
            float oa1 = __shfl_xor(a1[t], off, 64);
            float oa2 = __shfl_xor(a2[t], off, 64);
            int   oi1 = __shfl_xor(i1[t], off, 64);
            float lo  = fminf(a1[t], oa1);
            a2[t] = fmaxf(fmaxf(a2[t], oa2), lo);
            bool take = (oa1 > a1[t]) || (oa1 == a1[t] && oi1 < i1[t]);
            a1[t] = take ? oa1 : a1[t];
            i1[t] = take ? oi1 : i1[t];
        }

    // worklist append: header {oldidx, point} + coalesced z fp32 stash.
    // z lines are L1/L2-hot (fragment loads just touched them) -> cheap here,
    // and fixup's read becomes coalesced (4 lines) instead of 64-line scatter.
    unsigned m[2];
#pragma unroll
    for (int t = 0; t < 2; ++t) {
        bool flg = (a1[t] - a2[t]) <= FLAG_HALF;         // near-tie in approx metric
        m[t] = (unsigned)(__ballot(g == 0 && flg) & 0xFFFFull);
    }
    unsigned mask = m[0] | (m[1] << 16);
    int npts = __popc(mask);
    unsigned wbase = 0;
    if (lane == 0 && npts) wbase = atomicAdd(cnt, (unsigned)npts);
    wbase = __shfl(wbase, 0, 64);
    unsigned mm = mask;
    int k2 = 0;
    while (mm) {
        int idx = __ffs(mm) - 1; mm &= mm - 1;           // wave-uniform
        unsigned pos = wbase + (unsigned)k2; ++k2;
        if (pos < hcap) {
            int oldi = (idx & 16) ? __shfl(i1[1], idx & 15, 64)
                                  : __shfl(i1[0], idx & 15, 64);
            if (lane == 0)
                wlh[pos] = ((unsigned long long)(unsigned)oldi << 32)
                         | (unsigned)(pbase + idx);
            if (pos < zcap)
                wlz[(size_t)pos * 64 + lane] = zbase[(size_t)lane * HWc + idx];
        }
    }

    // epilogue: gather exact fp32 code rows, write z_q, loss from zh
    float lsum = 0.f;
#pragma unroll
    for (int t = 0; t < 2; ++t) {
        const float* er = emb + (size_t)i1[t] * Dc;
        float* op = out + (size_t)b * (Dc * HWc) + hw0 + t * 16 + p16;
#pragma unroll
        for (int c = 0; c < 2; ++c)
#pragma unroll
            for (int j = 0; j < 8; ++j) {
                int d = c * 32 + g * 8 + j;              // lane's own d-slots
                float e = er[d];
                op[(size_t)d * HWc] = e;
                float f = e - (float)zh[t][c][j];
                lsum = fmaf(f, f, lsum);
            }
    }

    // block-level loss reduction -> one atomic per block
    float v = lsum;
#pragma unroll
    for (int off = 32; off > 0; off >>= 1) v += __shfl_down(v, off);
    float* red = (float*)(smem + LDS_RED);
    if (lane == 0) red[wave] = v;
    __syncthreads();
    if (tid == 0) {
        float bs = 0.f;
#pragma unroll
        for (int w = 0; w < 16; ++w) bs += red[w];
        atomicAdd(acc, bs);
    }
}

// ---- K3: exact fp32 fixup — coalesced z, LDS codebook, write-only-if-flip --
// Compute loop is R14's byte-identical LDS scan (R1 accumulation order, same
// tie-break -> same decisions). New: z from the coalesced stash (fallback to
// gather beyond zcap); out written ONLY when the winner changed (loss delta
// from LDS rows, no out read).
__global__ __launch_bounds__(256) void vq_fixup(const float* __restrict__ z_e,
                                                const float* __restrict__ emb,
                                                const float* __restrict__ eposneg,
                                                const unsigned long long* __restrict__ wlh,
                                                const float* __restrict__ wlz,
                                                const unsigned int* __restrict__ cnt,
                                                unsigned int hcap, unsigned int zcap,
                                                float* __restrict__ out,
                                                float* __restrict__ acc) {
    extern __shared__ __align__(16) char fsm[];          // 128KB E-fp32 + 2KB epos
    __shared__ __align__(16) float zsh[4][4][64];        // [wave][slot][dim]
    const unsigned n = min(*cnt, hcap);
    const unsigned nch = (n + 3) >> 2;                   // chunks of 4 points
    if (blockIdx.x * 4 >= nch) return;                   // no work: skip staging

    // stage codebook (XOR-swizzled) + eposneg
    {
        const float4* e4 = reinterpret_cast<const float4*>(emb);
        for (int i = threadIdx.x; i < 8192; i += 256) {
            int row = i >> 4, q = i & 15;
            *reinterpret_cast<float4*>(fsm + row * 256 + ((q ^ (row & 15)) << 4)) = e4[i];
        }
        for (int i = threadIdx.x; i < Kc; i += 256)
            ((float*)(fsm + FX_EPOS))[i] = eposneg[i];
    }
    __syncthreads();
    const float* eposL = (const float*)(fsm + FX_EPOS);

    const int lane = threadIdx.x & 63;
    const int wv   = threadIdx.x >> 6;
    const int swz16 = (lane & 15) << 4;                  // code&15 == lane&15
    const unsigned wid = blockIdx.x * 4 + wv;
    const unsigned nw  = gridDim.x * 4;
    for (unsigned ch = wid; ch < nch; ch += nw) {
        const unsigned base = ch * 4;
        int pp[4], oldi[4];
#pragma unroll
        for (int s = 0; s < 4; ++s) {
            unsigned idx = base + (unsigned)s;
            if (idx >= n) idx = n - 1;                   // pad: dup last entry
            unsigned long long h = wlh[idx];
            pp[s]   = (int)(h & 0xFFFFFFFFull);
            oldi[s] = (int)(h >> 32);
            if (idx < zcap) {
                zsh[wv][s][lane] = wlz[(size_t)idx * 64 + lane];   // coalesced
            } else {                                     // fallback: gather
                int b = pp[s] >> 12, hw = pp[s] & 4095;
                zsh[wv][s][lane] = z_e[(size_t)b * (Dc * HWc) + (size_t)lane * HWc + hw];
            }
        }
        asm volatile("s_waitcnt lgkmcnt(0) vmcnt(0)" ::: "memory");

        float bd[4] = {3.4e38f, 3.4e38f, 3.4e38f, 3.4e38f};
        int   bi[4] = {0, 0, 0, 0};
#pragma unroll 1
        for (int r = 0; r < 8; ++r) {                    // codes r*64 + lane
            const int code = r * 64 + lane;
            const uintptr_t ebp = (uintptr_t)fsm + (unsigned)code * 256;
            float s0[4] = {0.f, 0.f, 0.f, 0.f}, s1[4] = {0.f, 0.f, 0.f, 0.f};
            float s2[4] = {0.f, 0.f, 0.f, 0.f}, s3[4] = {0.f, 0.f, 0.f, 0.f};
#pragma unroll
            for (int q = 0; q < 4; ++q) {                // d order 0..15 per chain
                float4 e0 = *reinterpret_cast<const float4*>(ebp + ((( q      << 4)) ^ swz16));
                float4 e1 = *reinterpret_cast<const float4*>(ebp + ((((4 + q) << 4)) ^ swz16));
                float4 e2 = *reinterpret_cast<const float4*>(ebp + ((((8 + q) << 4)) ^ swz16));
                float4 e3 = *reinterpret_cast<const float4*>(ebp + ((((12 + q) << 4)) ^ swz16));
#pragma unroll
                for (int s = 0; s < 4; ++s) {            // 4 points share the e row
                    const float4* z4 = reinterpret_cast<const float4*>(zsh[wv][s]);
                    float4 zz0 = z4[q],      zz1 = z4[4 + q];
                    float4 zz2 = z4[8 + q],  zz3 = z4[12 + q];
                    s0[s] = fmaf(e0.x, zz0.x, s0[s]); s0[s] = fmaf(e0.y, zz0.y, s0[s]);
                    s0[s] = fmaf(e0.z, zz0.z, s0[s]); s0[s] = fmaf(e0.w, zz0.w, s0[s]);
                    s1[s] = fmaf(e1.x, zz1.x, s1[s]); s1[s] = fmaf(e1.y, zz1.y, s1[s]);
                    s1[s] = fmaf(e1.z, zz1.z, s1[s]); s1[s] = fmaf(e1.w, zz1.w, s1[s]);
                    s2[s] = fmaf(e2.x, zz2.x, s2[s]); s2[s] = fmaf(e2.y, zz2.y, s2[s]);
                    s2[s] = fmaf(e2.z, zz2.z, s2[s]); s2[s] = fmaf(e2.w, zz2.w, s2[s]);
                    s3[s] = fmaf(e3.x, zz3.x, s3[s]); s3[s] = fmaf(e3.y, zz3.y, s3[s]);
                    s3[s] = fmaf(e3.z, zz3.z, s3[s]); s3[s] = fmaf(e3.w, zz3.w, s3[s]);
                }
            }
            const float en2 = -2.0f * eposL[code];       // +||e||^2 term
#pragma unroll
            for (int s = 0; s < 4; ++s) {
                float dot  = (s0[s] + s1[s]) + (s2[s] + s3[s]);
                float dist = fmaf(-2.0f, dot, en2);
                bool lt = dist < bd[s];                  // within-lane ascending
                bd[s] = lt ? dist : bd[s];
                bi[s] = lt ? code : bi[s];
            }
        }
        // per-slot cross-lane argmin; patch ONLY if the winner changed
#pragma unroll 1
        for (int s = 0; s < 4; ++s) {
            if (base + (unsigned)s >= n) break;
            float bds = bd[s]; int bis = bi[s];
#pragma unroll
            for (int off = 32; off > 0; off >>= 1) {
                float od = __shfl_xor(bds, off, 64);
                int   oi = __shfl_xor(bis, off, 64);
                bool take = (od < bds) || (od == bds && oi < bis);
                bds = take ? od : bds;
                bis = take ? oi : bis;
            }
            if (bis == oldi[s]) continue;                // approx winner was right
            int p = pp[s];
            int b = p >> 12, hw = p & 4095;
            // e_new / e_old dims from LDS (swizzled scalar reads; 2 lanes/bank)
            int qd = lane >> 2, od4 = (lane & 3) << 2;
            float en = *reinterpret_cast<const float*>(
                (uintptr_t)fsm + (unsigned)bis * 256 + (((qd ^ (bis & 15)) << 4) | od4));
            float eo = *reinterpret_cast<const float*>(
                (uintptr_t)fsm + (unsigned)oldi[s] * 256 + (((qd ^ (oldi[s] & 15)) << 4) | od4));
            float zf = zsh[wv][s][lane];
            out[(size_t)b * (Dc * HWc) + (size_t)lane * HWc + hw] = en;
            float dn = en - zf, dold = eo - zf;
            float delta = fmaf(dn, dn, -dold * dold);
#pragma unroll
            for (int off = 32; off > 0; off >>= 1) delta += __shfl_down(delta, off);
            if (lane == 0) atomicAdd(acc, delta);
        }
    }
}

// ---- K4: finalize loss -----------------------------------------------------
__global__ void vq_finalize(const float* __restrict__ acc, float* __restrict__ out_loss) {
    out_loss[0] = 1.25f * (acc[0] * INV_ELEMS);
}

extern "C" void kernel_launch(void* const* d_in, const int* in_sizes, int n_in,
                              void* d_out, int out_size, void* d_ws, size_t ws_size,
                              hipStream_t stream) {
    const float* z_e = (const float*)d_in[0];
    const float* emb = (const float*)d_in[1];
    float* out = (float*)d_out;

    char* ws = (char*)d_ws;
    float*              acc     = (float*)(ws);          // 4 B
    unsigned*           cnt     = (unsigned*)(ws + 4);   // 4 B worklist counter
    float*              eposneg = (float*)(ws + 256);    // 512 f32 = 2 KB
    short*              EF      = (short*)(ws + 4096);   // 64 KB fp16 fragments
    unsigned long long* wlh     = (unsigned long long*)(ws + WL_H_OFF);
    float*              wlz     = (float*)(ws + WL_Z_OFF);

    unsigned hcap = 0, zcap = 0;
    if (ws_size > (size_t)WL_H_OFF + 8)
        hcap = (unsigned)min((size_t)32768, (ws_size - WL_H_OFF) / 8);
    if (ws_size > (size_t)WL_Z_OFF + 256)
        zcap = (unsigned)min((size_t)32768, (ws_size - WL_Z_OFF) / 256);

    hipFuncSetAttribute(reinterpret_cast<const void*>(vq_main),
                        hipFuncAttributeMaxDynamicSharedMemorySize, LDS_TOT);
    hipFuncSetAttribute(reinterpret_cast<const void*>(vq_fixup),
                        hipFuncAttributeMaxDynamicSharedMemorySize, FX_TOT);

    hipMemsetAsync(ws, 0, 8, stream);                    // acc + cnt
    vq_prep<<<18, 256, 0, stream>>>(emb, EF, eposneg);
    vq_main<<<Nc / 512, 1024, LDS_TOT, stream>>>(z_e, emb, EF, eposneg, out, acc,
                                                 cnt, wlh, wlz, hcap, zcap);
    vq_fixup<<<256, 256, FX_TOT, stream>>>(z_e, emb, eposneg, wlh, wlz, cnt,
                                           hcap, zcap, out, acc);
    vq_finalize<<<1, 1, 0, stream>>>(acc, out + (size_t)Nc * Dc);
}